// Round 1
// baseline (32839.395 us; speedup 1.0000x reference)
//
#include <hip/hip_runtime.h>
#include <math.h>

#define BB 64
#define LATENT 256
#define TARGETD 128
#define ACTD 6
#define HIDD 512
#define DST 16

// ---------------- output offsets (floats) ----------------
#define O_PRED   0
#define O_ZT     4194304
#define O_STATE  4210688
#define O_MUP    4734976
#define O_LVP    4751360
#define O_MUPO   4767744
#define O_LVPO   4784128

// ---------------- ws offsets (floats) ----------------
#define W_SSMIN  0u
#define W_DELTA  32768u
#define W_BT     65536u
#define W_CT     66560u
#define W_BELIEF 67584u
#define W_CNN    100352u
#define W_ENCP   133120u            // 512*32*64 = 1,048,576
#define W_H1     1181696u           // 33,554,432
#define W_H2     34736128u          // 16,777,216
#define W_H3     51513344u          // 8,388,608
#define W_H4T    59901952u          // 4,194,304
// reuse: dec = W_H2, d1 = W_H2+2097152, d2 = W_H1, d3 = W_H1+8388608
#define W_DEC    (W_H2)
#define W_D1     (W_H2 + 2097152u)
#define W_D2     (W_H1)
#define W_D3     (W_H1 + 8388608u)

#define ENC_OT 16
#define ENC_NS 32

// ================= SSM / small dense =================

__global__ void k_ssm_in(const float* __restrict__ z_prev, const float* __restrict__ act,
                         const float* __restrict__ w, const float* __restrict__ bias,
                         float* __restrict__ out) {
  int id = blockIdx.x * blockDim.x + threadIdx.x;
  int b = id >> 9, h = id & 511;
  const float* wr = w + (size_t)h * (LATENT + ACTD);
  const float* zr = z_prev + (size_t)b * LATENT;
  float acc = bias[h];
  #pragma unroll 4
  for (int k = 0; k < LATENT; ++k) acc += zr[k] * wr[k];
  const float* ar = act + (size_t)b * ACTD;
  #pragma unroll
  for (int k = 0; k < ACTD; ++k) acc += ar[k] * wr[LATENT + k];
  out[id] = acc / (1.f + expf(-acc));   // silu
}

__global__ void k_delta(const float* __restrict__ ssm_in, const float* __restrict__ w,
                        const float* __restrict__ bias, float* __restrict__ out) {
  int id = blockIdx.x * blockDim.x + threadIdx.x;
  int b = id >> 9, h = id & 511;
  const float* xr = ssm_in + (size_t)b * HIDD;
  const float* wr = w + (size_t)h * HIDD;
  float acc = bias[h];
  #pragma unroll 4
  for (int k = 0; k < HIDD; ++k) acc += xr[k] * wr[k];
  // softplus, stable
  out[id] = fmaxf(acc, 0.f) + log1pf(expf(-fabsf(acc)));
}

__global__ void k_bc(const float* __restrict__ ssm_in, const float* __restrict__ Bw,
                     const float* __restrict__ Cw, float* __restrict__ Bt,
                     float* __restrict__ Ct) {
  int id = blockIdx.x * blockDim.x + threadIdx.x;   // B*16
  if (id >= BB * DST) return;
  int b = id >> 4, n = id & 15;
  const float* xr = ssm_in + (size_t)b * HIDD;
  const float* br = Bw + (size_t)n * HIDD;
  const float* cr = Cw + (size_t)n * HIDD;
  float ab = 0.f, ac = 0.f;
  #pragma unroll 4
  for (int k = 0; k < HIDD; ++k) { ab += xr[k] * br[k]; ac += xr[k] * cr[k]; }
  Bt[id] = ab; Ct[id] = ac;
}

__global__ void k_state(const float* __restrict__ Delta, const float* __restrict__ ssm_in,
                        const float* __restrict__ A_log, const float* __restrict__ Bt,
                        const float* __restrict__ Ct, const float* __restrict__ Dv,
                        const float* __restrict__ prev, float* __restrict__ state_out,
                        float* __restrict__ belief) {
  int id = blockIdx.x * blockDim.x + threadIdx.x;
  int b = id >> 9, h = id & 511;
  float d = Delta[id], si = ssm_in[id];
  float bel = Dv[h] * si;
  const float* al = A_log + (size_t)h * DST;
  const float* bt = Bt + (size_t)b * DST;
  const float* ct = Ct + (size_t)b * DST;
  const float* sp = prev + (size_t)id * DST;
  float* so = state_out + (size_t)id * DST;
  #pragma unroll
  for (int n = 0; n < DST; ++n) {
    float A = -expf(al[n]);
    float st = expf(d * A) * sp[n] + d * bt[n] * si;
    so[n] = st;
    bel += st * ct[n];
  }
  belief[id] = bel;
}

__global__ void k_prior(const float* __restrict__ belief, const float* __restrict__ w,
                        const float* __restrict__ bias, float* __restrict__ out) {
  int id = blockIdx.x * blockDim.x + threadIdx.x;
  int b = id >> 9, j = id & 511;
  const float* xr = belief + (size_t)b * HIDD;
  const float* wr = w + (size_t)j * HIDD;
  float acc = bias[j];
  #pragma unroll 4
  for (int k = 0; k < HIDD; ++k) acc += xr[k] * wr[k];
  if (j < 256) out[O_MUP + b * 256 + j] = acc;
  else         out[O_LVP + b * 256 + (j - 256)] = acc;
}

// ================= conv 4x4 stride2 pad1 + relu =================

__global__ void conv4x4s2(const float* __restrict__ in, const float* __restrict__ w,
                          const float* __restrict__ bias, float* __restrict__ out,
                          int Cin, int Hin, int Win, int Cout, int Hout, int Wout,
                          int transOut) {
  int id = blockIdx.x * blockDim.x + threadIdx.x;
  int W4 = Wout >> 2;
  int x4 = id % W4; int t = id / W4;
  int oy = t % Hout; t /= Hout;
  int co = t % Cout; int b = t / Cout;
  if (b >= BB) return;
  int ox0 = x4 * 4;
  float bv = bias[co];
  float a0 = bv, a1 = bv, a2 = bv, a3 = bv;
  const float* wc = w + (size_t)co * Cin * 16;
  for (int ci = 0; ci < Cin; ++ci) {
    const float* ip = in + ((size_t)(b * Cin + ci) * Hin) * Win;
    const float* wp = wc + ci * 16;
    #pragma unroll
    for (int ky = 0; ky < 4; ++ky) {
      int iy = oy * 2 - 1 + ky;
      if ((unsigned)iy >= (unsigned)Hin) continue;
      const float* row = ip + (size_t)iy * Win;
      float x[10];
      int ixb = ox0 * 2 - 1;
      #pragma unroll
      for (int j = 0; j < 10; ++j) {
        int ix = ixb + j;
        x[j] = ((unsigned)ix < (unsigned)Win) ? row[ix] : 0.f;
      }
      float w0 = wp[ky*4+0], w1 = wp[ky*4+1], w2 = wp[ky*4+2], w3 = wp[ky*4+3];
      a0 += x[0]*w0 + x[1]*w1 + x[2]*w2 + x[3]*w3;
      a1 += x[2]*w0 + x[3]*w1 + x[4]*w2 + x[5]*w3;
      a2 += x[4]*w0 + x[5]*w1 + x[6]*w2 + x[7]*w3;
      a3 += x[6]*w0 + x[7]*w1 + x[8]*w2 + x[9]*w3;
    }
  }
  a0 = fmaxf(a0, 0.f); a1 = fmaxf(a1, 0.f); a2 = fmaxf(a2, 0.f); a3 = fmaxf(a3, 0.f);
  if (!transOut) {
    size_t o = ((size_t)(b * Cout + co) * Hout + oy) * Wout + ox0;
    float4 v; v.x = a0; v.y = a1; v.z = a2; v.w = a3;
    *(float4*)(out + o) = v;
  } else {
    int k0 = (co * Hout + oy) * Wout + ox0;
    out[(size_t)(k0 + 0) * 64 + b] = a0;
    out[(size_t)(k0 + 1) * 64 + b] = a1;
    out[(size_t)(k0 + 2) * 64 + b] = a2;
    out[(size_t)(k0 + 3) * 64 + b] = a3;
  }
}

// ================= transposed conv 4x4 stride2 pad1 =================
// out[b,co,oy,ox] = bias + sum_ci sum over 2 valid rows (P=p0,p0+2) x 2 valid cols

__global__ void deconv4x4s2(const float* __restrict__ in, const float* __restrict__ w,
                            const float* __restrict__ bias, float* __restrict__ out,
                            int Cin, int Hin, int Win, int Cout, int Hout, int Wout,
                            int doRelu) {
  int id = blockIdx.x * blockDim.x + threadIdx.x;
  int W4 = Wout >> 2;
  int x4 = id % W4; int t = id / W4;
  int oy = t % Hout; t /= Hout;
  int co = t % Cout; int b = t / Cout;
  if (b >= BB) return;
  int ox0 = x4 * 4;
  int p0 = (oy + 1) & 1;
  int iy_hi = (oy + 1 - p0) >> 1;  // weight row p0
  int iy_lo = iy_hi - 1;           // weight row p0+2
  int ixb = (ox0 >> 1) - 1;
  float bv = bias[co];
  float a0 = bv, a1 = bv, a2 = bv, a3 = bv;
  for (int ci = 0; ci < Cin; ++ci) {
    const float* wp = w + (size_t)(ci * Cout + co) * 16;
    const float* ipb = in + ((size_t)(b * Cin + ci) * Hin) * Win;
    #pragma unroll
    for (int r = 0; r < 2; ++r) {
      int iy = r ? iy_hi : iy_lo;
      int p = r ? p0 : (p0 + 2);
      if ((unsigned)iy >= (unsigned)Hin) continue;
      const float* row = ipb + (size_t)iy * Win;
      float xv[4];
      #pragma unroll
      for (int i = 0; i < 4; ++i) {
        int ix = ixb + i;
        xv[i] = ((unsigned)ix < (unsigned)Win) ? row[ix] : 0.f;
      }
      float q0 = wp[p*4+0], q1 = wp[p*4+1], q2 = wp[p*4+2], q3 = wp[p*4+3];
      a0 += xv[1]*q1 + xv[0]*q3;
      a1 += xv[2]*q0 + xv[1]*q2;
      a2 += xv[2]*q1 + xv[1]*q3;
      a3 += xv[3]*q0 + xv[2]*q2;
    }
  }
  if (doRelu) { a0=fmaxf(a0,0.f); a1=fmaxf(a1,0.f); a2=fmaxf(a2,0.f); a3=fmaxf(a3,0.f); }
  size_t o = ((size_t)(b * Cout + co) * Hout + oy) * Wout + ox0;
  float4 v; v.x = a0; v.y = a1; v.z = a2; v.w = a3;
  *(float4*)(out + o) = v;
}

// ================= enc_fc : cnn_feat = relu(hT^T @ W^T + b) =================
// hT: (65536, 64) transposed activations; W: (512, 65536)

__global__ __launch_bounds__(64) void k_encfc(const float* __restrict__ hT,
                                              const float* __restrict__ w,
                                              float* __restrict__ partial) {
  int bid = blockIdx.x;          // (512/ENC_OT) * ENC_NS
  int og = bid / ENC_NS;
  int s = bid % ENC_NS;
  int o0 = og * ENC_OT;
  int lane = threadIdx.x;        // = batch
  int kc = 65536 / ENC_NS;       // 2048
  int k0 = s * kc;
  float acc[ENC_OT];
  #pragma unroll
  for (int i = 0; i < ENC_OT; ++i) acc[i] = 0.f;
  for (int k = k0; k < k0 + kc; ++k) {
    float hv = hT[(size_t)k * 64 + lane];
    #pragma unroll
    for (int i = 0; i < ENC_OT; ++i)
      acc[i] += hv * w[(size_t)(o0 + i) * 65536 + k];
  }
  #pragma unroll
  for (int i = 0; i < ENC_OT; ++i)
    partial[(size_t)((o0 + i) * ENC_NS + s) * 64 + lane] = acc[i];
}

__global__ void k_encfc_red(const float* __restrict__ partial, const float* __restrict__ bias,
                            float* __restrict__ cnn) {
  int id = blockIdx.x * blockDim.x + threadIdx.x;  // b*512+o
  int b = id >> 9, o = id & 511;
  float acc = bias[o];
  #pragma unroll
  for (int s = 0; s < ENC_NS; ++s) acc += partial[(size_t)(o * ENC_NS + s) * 64 + b];
  cnn[id] = fmaxf(acc, 0.f);
}

// ================= posterior / reparam =================

__global__ void k_post(const float* __restrict__ cnn, const float* __restrict__ belief,
                       const float* __restrict__ w, const float* __restrict__ bias,
                       float* __restrict__ out) {
  int id = blockIdx.x * blockDim.x + threadIdx.x;
  int b = id >> 9, j = id & 511;
  const float* wr = w + (size_t)j * 1024;
  const float* cr = cnn + (size_t)b * HIDD;
  const float* br = belief + (size_t)b * HIDD;
  float acc = bias[j];
  #pragma unroll 4
  for (int k = 0; k < HIDD; ++k) acc += cr[k] * wr[k];
  #pragma unroll 4
  for (int k = 0; k < HIDD; ++k) acc += br[k] * wr[512 + k];
  if (j < 256) out[O_MUPO + b * 256 + j] = acc;
  else         out[O_LVPO + b * 256 + (j - 256)] = acc;
}

__global__ void k_z(const float* __restrict__ eps, float* __restrict__ out) {
  int id = blockIdx.x * blockDim.x + threadIdx.x;  // B*256
  int b = id >> 8, i = id & 255;
  float mu = out[O_MUPO + b * 256 + i];
  float lv = out[O_LVPO + b * 256 + i];
  out[O_ZT + b * 256 + i] = mu + eps[id] * expf(0.5f * lv);
}

// ================= dec_fc : (64,128) @ (32768,128)^T =================

__global__ __launch_bounds__(256) void k_decfc(const float* __restrict__ z,
                                               const float* __restrict__ w,
                                               const float* __restrict__ bias,
                                               float* __restrict__ dec) {
  int t = threadIdx.x;
  int b = t & 63;
  int m = blockIdx.x * 4 + (t >> 6);
  const float* wr = w + (size_t)m * 128;
  const float* zr = z + (size_t)b * 256;   // z_t row; first 128 = z_target
  float acc = bias[m];
  #pragma unroll 8
  for (int k = 0; k < 128; ++k) acc += zr[k] * wr[k];
  dec[(size_t)b * 32768 + m] = acc;
}

// ================= launch =================

extern "C" void kernel_launch(void* const* d_in, const int* in_sizes, int n_in,
                              void* d_out, int out_size, void* d_ws, size_t ws_size,
                              hipStream_t stream) {
  const float* img      = (const float*)d_in[0];
  const float* act      = (const float*)d_in[1];
  const float* z_prev   = (const float*)d_in[2];
  const float* st_prev  = (const float*)d_in[3];
  const float* eps      = (const float*)d_in[4];
  const float* c1w = (const float*)d_in[5];  const float* c1b = (const float*)d_in[6];
  const float* c2w = (const float*)d_in[7];  const float* c2b = (const float*)d_in[8];
  const float* c3w = (const float*)d_in[9];  const float* c3b = (const float*)d_in[10];
  const float* c4w = (const float*)d_in[11]; const float* c4b = (const float*)d_in[12];
  const float* efw = (const float*)d_in[13]; const float* efb = (const float*)d_in[14];
  const float* pow_ = (const float*)d_in[15]; const float* pob = (const float*)d_in[16];
  const float* prw = (const float*)d_in[17]; const float* prb = (const float*)d_in[18];
  const float* siw = (const float*)d_in[19]; const float* sib = (const float*)d_in[20];
  const float* Alog = (const float*)d_in[21];
  const float* Bw = (const float*)d_in[22];  const float* Cw = (const float*)d_in[23];
  const float* Dw = (const float*)d_in[24];  const float* Db = (const float*)d_in[25];
  const float* Dv = (const float*)d_in[26];
  const float* dfw = (const float*)d_in[27]; const float* dfb = (const float*)d_in[28];
  const float* d1w = (const float*)d_in[29]; const float* d1b = (const float*)d_in[30];
  const float* d2w = (const float*)d_in[31]; const float* d2b = (const float*)d_in[32];
  const float* d3w = (const float*)d_in[33]; const float* d3b = (const float*)d_in[34];
  const float* d4w = (const float*)d_in[35]; const float* d4b = (const float*)d_in[36];

  float* ws = (float*)d_ws;
  float* out = (float*)d_out;

  // ---- SSM chain ----
  k_ssm_in<<<128, 256, 0, stream>>>(z_prev, act, siw, sib, ws + W_SSMIN);
  k_delta<<<128, 256, 0, stream>>>(ws + W_SSMIN, Dw, Db, ws + W_DELTA);
  k_bc<<<4, 256, 0, stream>>>(ws + W_SSMIN, Bw, Cw, ws + W_BT, ws + W_CT);
  k_state<<<128, 256, 0, stream>>>(ws + W_DELTA, ws + W_SSMIN, Alog, ws + W_BT,
                                   ws + W_CT, Dv, st_prev, out + O_STATE, ws + W_BELIEF);
  k_prior<<<128, 256, 0, stream>>>(ws + W_BELIEF, prw, prb, out);

  // ---- encoder convs ----
  conv4x4s2<<<32768, 256, 0, stream>>>(img, c1w, c1b, ws + W_H1, 3, 256, 256, 32, 128, 128, 0);
  conv4x4s2<<<16384, 256, 0, stream>>>(ws + W_H1, c2w, c2b, ws + W_H2, 32, 128, 128, 64, 64, 64, 0);
  conv4x4s2<<<8192, 256, 0, stream>>>(ws + W_H2, c3w, c3b, ws + W_H3, 64, 64, 64, 128, 32, 32, 0);
  conv4x4s2<<<4096, 256, 0, stream>>>(ws + W_H3, c4w, c4b, ws + W_H4T, 128, 32, 32, 256, 16, 16, 1);

  // ---- enc_fc ----
  k_encfc<<<(512 / ENC_OT) * ENC_NS, 64, 0, stream>>>(ws + W_H4T, efw, ws + W_ENCP);
  k_encfc_red<<<128, 256, 0, stream>>>(ws + W_ENCP, efb, ws + W_CNN);

  // ---- posterior + reparam ----
  k_post<<<128, 256, 0, stream>>>(ws + W_CNN, ws + W_BELIEF, pow_, pob, out);
  k_z<<<64, 256, 0, stream>>>(eps, out);

  // ---- decoder ----
  k_decfc<<<8192, 256, 0, stream>>>(out + O_ZT, dfw, dfb, ws + W_DEC);
  deconv4x4s2<<<4096, 256, 0, stream>>>(ws + W_DEC, d1w, d1b, ws + W_D1, 128, 16, 16, 64, 32, 32, 1);
  deconv4x4s2<<<8192, 256, 0, stream>>>(ws + W_D1, d2w, d2b, ws + W_D2, 64, 32, 32, 32, 64, 64, 1);
  deconv4x4s2<<<16384, 256, 0, stream>>>(ws + W_D2, d3w, d3b, ws + W_D3, 32, 64, 64, 16, 128, 128, 1);
  deconv4x4s2<<<4096, 256, 0, stream>>>(ws + W_D3, d4w, d4b, out + O_PRED, 16, 128, 128, 1, 256, 256, 0);
}

// Round 2
// 4835.792 us; speedup vs baseline: 6.7909x; 6.7909x over previous
//
#include <hip/hip_runtime.h>
#include <math.h>

#define BB 64
#define LATENT 256
#define ACTD 6
#define HIDD 512
#define DST 16

// ---------------- output offsets (floats) ----------------
#define O_PRED   0
#define O_ZT     4194304
#define O_STATE  4210688
#define O_MUP    4734976
#define O_LVP    4751360
#define O_MUPO   4767744
#define O_LVPO   4784128

// ---------------- ws offsets (floats), lifetime-reused ----------------
#define W_SSMIN  0u
#define W_DELTA  32768u
#define W_BT     65536u
#define W_CT     66560u
#define W_BELIEF 67584u
#define W_CNN    100352u
// big regions
#define W_H1     1181696u                 // 33,554,432  [1.18M .. 34.74M)
#define W_TIMG   34736128u                // 12,582,912  [34.74M .. 47.32M)
#define W_H2     47319040u                // 16,777,216  [47.32M .. 64.10M)
#define W_H3     1181696u                 // 8,388,608   reuse H1 (h1 dead)
#define W_H4T    9570304u                 // 4,194,304   reuse H1 tail
#define W_ENCP   34736128u                // 2,097,152   reuse TIMG (dead)
#define W_DEC    38930432u                // 2,097,152   TIMG region
#define W_D1     41027584u                // 4,194,304   TIMG region (fits: ends 45.22M)
#define W_D2     47319040u                // 8,388,608   reuse H2
#define W_D3     1181696u                 // 16,777,216  reuse H1 (h3/h4t dead)
#define W_PREDT  38930432u                // 4,194,304   reuse DEC (dead)

#define ENC_OT 16
#define ENC_NS 64

// ================= SSM / small dense (unchanged, small) =================

__global__ void k_ssm_in(const float* __restrict__ z_prev, const float* __restrict__ act,
                         const float* __restrict__ w, const float* __restrict__ bias,
                         float* __restrict__ out) {
  int id = blockIdx.x * blockDim.x + threadIdx.x;
  int b = id >> 9, h = id & 511;
  const float* wr = w + (size_t)h * (LATENT + ACTD);
  const float* zr = z_prev + (size_t)b * LATENT;
  float acc = bias[h];
  #pragma unroll 4
  for (int k = 0; k < LATENT; ++k) acc += zr[k] * wr[k];
  const float* ar = act + (size_t)b * ACTD;
  #pragma unroll
  for (int k = 0; k < ACTD; ++k) acc += ar[k] * wr[LATENT + k];
  out[id] = acc / (1.f + expf(-acc));   // silu
}

__global__ void k_delta(const float* __restrict__ ssm_in, const float* __restrict__ w,
                        const float* __restrict__ bias, float* __restrict__ out) {
  int id = blockIdx.x * blockDim.x + threadIdx.x;
  int b = id >> 9, h = id & 511;
  const float* xr = ssm_in + (size_t)b * HIDD;
  const float* wr = w + (size_t)h * HIDD;
  float acc = bias[h];
  #pragma unroll 4
  for (int k = 0; k < HIDD; ++k) acc += xr[k] * wr[k];
  out[id] = fmaxf(acc, 0.f) + log1pf(expf(-fabsf(acc)));  // stable softplus
}

__global__ void k_bc(const float* __restrict__ ssm_in, const float* __restrict__ Bw,
                     const float* __restrict__ Cw, float* __restrict__ Bt,
                     float* __restrict__ Ct) {
  int id = blockIdx.x * blockDim.x + threadIdx.x;   // B*16
  if (id >= BB * DST) return;
  int b = id >> 4, n = id & 15;
  const float* xr = ssm_in + (size_t)b * HIDD;
  const float* br = Bw + (size_t)n * HIDD;
  const float* cr = Cw + (size_t)n * HIDD;
  float ab = 0.f, ac = 0.f;
  #pragma unroll 4
  for (int k = 0; k < HIDD; ++k) { ab += xr[k] * br[k]; ac += xr[k] * cr[k]; }
  Bt[id] = ab; Ct[id] = ac;
}

__global__ void k_state(const float* __restrict__ Delta, const float* __restrict__ ssm_in,
                        const float* __restrict__ A_log, const float* __restrict__ Bt,
                        const float* __restrict__ Ct, const float* __restrict__ Dv,
                        const float* __restrict__ prev, float* __restrict__ state_out,
                        float* __restrict__ belief) {
  int id = blockIdx.x * blockDim.x + threadIdx.x;
  int b = id >> 9, h = id & 511;
  float d = Delta[id], si = ssm_in[id];
  float bel = Dv[h] * si;
  const float* al = A_log + (size_t)h * DST;
  const float* bt = Bt + (size_t)b * DST;
  const float* ct = Ct + (size_t)b * DST;
  const float* sp = prev + (size_t)id * DST;
  float* so = state_out + (size_t)id * DST;
  #pragma unroll
  for (int n = 0; n < DST; ++n) {
    float A = -expf(al[n]);
    float st = expf(d * A) * sp[n] + d * bt[n] * si;
    so[n] = st;
    bel += st * ct[n];
  }
  belief[id] = bel;
}

__global__ void k_prior(const float* __restrict__ belief, const float* __restrict__ w,
                        const float* __restrict__ bias, float* __restrict__ out) {
  int id = blockIdx.x * blockDim.x + threadIdx.x;
  int b = id >> 9, j = id & 511;
  const float* xr = belief + (size_t)b * HIDD;
  const float* wr = w + (size_t)j * HIDD;
  float acc = bias[j];
  #pragma unroll 4
  for (int k = 0; k < HIDD; ++k) acc += xr[k] * wr[k];
  if (j < 256) out[O_MUP + b * 256 + j] = acc;
  else         out[O_LVP + b * 256 + (j - 256)] = acc;
}

// ================= layout transposes =================
// img [B,3,256,256] -> timg [3, 65536, B]
__global__ __launch_bounds__(256) void k_timg(const float* __restrict__ img,
                                              float* __restrict__ timg) {
  int blk = blockIdx.x;
  int c = blk >> 10, p0 = (blk & 1023) << 6;
  __shared__ float t[64 * 65];
  int tid = threadIdx.x;
  #pragma unroll
  for (int i = 0; i < 16; ++i) {
    int idx = tid + i * 256;
    int b = idx >> 6, pr = idx & 63;
    t[pr * 65 + b] = img[((size_t)b * 3 + c) * 65536 + p0 + pr];
  }
  __syncthreads();
  #pragma unroll
  for (int i = 0; i < 16; ++i) {
    int idx = tid + i * 256;
    int pr = idx >> 6, b = idx & 63;
    timg[((size_t)c * 65536 + p0 + pr) * 64 + b] = t[pr * 65 + b];
  }
}

// predT [65536, B] -> out [B, 65536]
__global__ __launch_bounds__(256) void k_tout(const float* __restrict__ predT,
                                              float* __restrict__ out) {
  int p0 = blockIdx.x << 6;
  __shared__ float t[64 * 65];
  int tid = threadIdx.x;
  #pragma unroll
  for (int i = 0; i < 16; ++i) {
    int idx = tid + i * 256;
    int pr = idx >> 6, b = idx & 63;
    t[pr * 65 + b] = predT[(size_t)(p0 + pr) * 64 + b];
  }
  __syncthreads();
  #pragma unroll
  for (int i = 0; i < 16; ++i) {
    int idx = tid + i * 256;
    int b = idx >> 6, pr = idx & 63;
    out[(size_t)b * 65536 + p0 + pr] = t[pr * 65 + b];
  }
}

// ================= conv 4x4 s2 p1 + relu, batch-inner layout =================
// in [Cin,Hin,Win,64], w [Cout,Cin,4,4], out [Cout,Hout,Wout,64]
// wave = (co-group of CT, oy, ox-group of 4); lane = batch
template<int CT>
__global__ __launch_bounds__(256) void conv_bt(const float* __restrict__ in,
                                               const float* __restrict__ w,
                                               const float* __restrict__ bias,
                                               float* __restrict__ out,
                                               int Cin, int Hin, int Win,
                                               int Cout, int Hout, int Wout) {
  int wid = __builtin_amdgcn_readfirstlane(blockIdx.x * 4 + (threadIdx.x >> 6));
  int lane = threadIdx.x & 63;
  int nx4 = Wout >> 2;
  int x4 = wid % nx4; int t = wid / nx4;
  int oy = t % Hout; int cg = t / Hout;
  int co0 = cg * CT;
  if (co0 >= Cout) return;
  int ox0 = x4 << 2;
  int ixb = ox0 * 2 - 1;
  float acc[CT][4];
  #pragma unroll
  for (int u = 0; u < CT; ++u) {
    float bv = bias[co0 + u];
    #pragma unroll
    for (int j = 0; j < 4; ++j) acc[u][j] = bv;
  }
  for (int ci = 0; ci < Cin; ++ci) {
    const float* ip = in + ((size_t)ci * Hin * Win) * 64 + lane;
    const float* wp = w + ((size_t)co0 * Cin + ci) * 16;
    #pragma unroll
    for (int ky = 0; ky < 4; ++ky) {
      int iy = oy * 2 - 1 + ky;
      if ((unsigned)iy >= (unsigned)Hin) continue;
      const float* rp = ip + (size_t)iy * Win * 64;
      float x[10];
      #pragma unroll
      for (int j = 0; j < 10; ++j) {
        int ix = ixb + j;
        x[j] = ((unsigned)ix < (unsigned)Win) ? rp[(size_t)ix * 64] : 0.f;
      }
      #pragma unroll
      for (int u = 0; u < CT; ++u) {
        const float* wq = wp + (size_t)u * Cin * 16 + ky * 4;
        float w0 = wq[0], w1 = wq[1], w2 = wq[2], w3 = wq[3];
        acc[u][0] += x[0]*w0 + x[1]*w1 + x[2]*w2 + x[3]*w3;
        acc[u][1] += x[2]*w0 + x[3]*w1 + x[4]*w2 + x[5]*w3;
        acc[u][2] += x[4]*w0 + x[5]*w1 + x[6]*w2 + x[7]*w3;
        acc[u][3] += x[6]*w0 + x[7]*w1 + x[8]*w2 + x[9]*w3;
      }
    }
  }
  #pragma unroll
  for (int u = 0; u < CT; ++u) {
    size_t ob = (((size_t)(co0 + u) * Hout + oy) * Wout + ox0) * 64 + lane;
    #pragma unroll
    for (int j = 0; j < 4; ++j) out[ob + (size_t)j * 64] = fmaxf(acc[u][j], 0.f);
  }
}

// ================= transposed conv 4x4 s2 p1, batch-inner layout =================
// in [Cin,Hin,Win,64], w [Cin,Cout,4,4], out [Cout,Hout,Wout,64]
template<int CT, bool RELU>
__global__ __launch_bounds__(256) void deconv_bt(const float* __restrict__ in,
                                                 const float* __restrict__ w,
                                                 const float* __restrict__ bias,
                                                 float* __restrict__ out,
                                                 int Cin, int Hin, int Win,
                                                 int Cout, int Hout, int Wout) {
  int wid = __builtin_amdgcn_readfirstlane(blockIdx.x * 4 + (threadIdx.x >> 6));
  int lane = threadIdx.x & 63;
  int nx4 = Wout >> 2;
  int x4 = wid % nx4; int t = wid / nx4;
  int oy = t % Hout; int cg = t / Hout;
  int co0 = cg * CT;
  if (co0 >= Cout) return;
  int ox0 = x4 << 2;
  int p0 = (oy + 1) & 1;
  int iy_hi = (oy + 1 - p0) >> 1;
  int iy_lo = iy_hi - 1;
  int ixb = (ox0 >> 1) - 1;
  float acc[CT][4];
  #pragma unroll
  for (int u = 0; u < CT; ++u) {
    float bv = bias[co0 + u];
    #pragma unroll
    for (int j = 0; j < 4; ++j) acc[u][j] = bv;
  }
  for (int ci = 0; ci < Cin; ++ci) {
    const float* ipb = in + ((size_t)ci * Hin * Win) * 64 + lane;
    const float* wcb = w + ((size_t)ci * Cout + co0) * 16;
    #pragma unroll
    for (int r = 0; r < 2; ++r) {
      int iy = r ? iy_hi : iy_lo;
      int p = r ? p0 : (p0 + 2);
      if ((unsigned)iy >= (unsigned)Hin) continue;
      const float* rp = ipb + (size_t)iy * Win * 64;
      float xv[4];
      #pragma unroll
      for (int i = 0; i < 4; ++i) {
        int ix = ixb + i;
        xv[i] = ((unsigned)ix < (unsigned)Win) ? rp[(size_t)ix * 64] : 0.f;
      }
      #pragma unroll
      for (int u = 0; u < CT; ++u) {
        const float* wq = wcb + (size_t)u * 16 + p * 4;
        float q0 = wq[0], q1 = wq[1], q2 = wq[2], q3 = wq[3];
        acc[u][0] += xv[1]*q1 + xv[0]*q3;
        acc[u][1] += xv[2]*q0 + xv[1]*q2;
        acc[u][2] += xv[2]*q1 + xv[1]*q3;
        acc[u][3] += xv[3]*q0 + xv[2]*q2;
      }
    }
  }
  #pragma unroll
  for (int u = 0; u < CT; ++u) {
    size_t ob = (((size_t)(co0 + u) * Hout + oy) * Wout + ox0) * 64 + lane;
    #pragma unroll
    for (int j = 0; j < 4; ++j) {
      float v = acc[u][j];
      if (RELU) v = fmaxf(v, 0.f);
      out[ob + (size_t)j * 64] = v;
    }
  }
}

// ================= enc_fc : k-split partials =================
// hT: (65536, 64); W: (512, 65536)
__global__ __launch_bounds__(64) void k_encfc(const float* __restrict__ hT,
                                              const float* __restrict__ w,
                                              float* __restrict__ partial) {
  int bid = blockIdx.x;
  int og = bid / ENC_NS;
  int s = bid % ENC_NS;
  int o0 = og * ENC_OT;
  int lane = threadIdx.x;        // = batch
  int kc = 65536 / ENC_NS;
  int k0 = s * kc;
  float acc[ENC_OT];
  #pragma unroll
  for (int i = 0; i < ENC_OT; ++i) acc[i] = 0.f;
  for (int k = k0; k < k0 + kc; ++k) {
    float hv = hT[(size_t)k * 64 + lane];
    #pragma unroll
    for (int i = 0; i < ENC_OT; ++i)
      acc[i] += hv * w[(size_t)(o0 + i) * 65536 + k];
  }
  #pragma unroll
  for (int i = 0; i < ENC_OT; ++i)
    partial[(size_t)((o0 + i) * ENC_NS + s) * 64 + lane] = acc[i];
}

__global__ void k_encfc_red(const float* __restrict__ partial, const float* __restrict__ bias,
                            float* __restrict__ cnn) {
  int id = blockIdx.x * blockDim.x + threadIdx.x;  // b*512+o
  int b = id >> 9, o = id & 511;
  float acc = bias[o];
  #pragma unroll
  for (int s = 0; s < ENC_NS; ++s) acc += partial[(size_t)(o * ENC_NS + s) * 64 + b];
  cnn[id] = fmaxf(acc, 0.f);
}

// ================= posterior / reparam =================

__global__ void k_post(const float* __restrict__ cnn, const float* __restrict__ belief,
                       const float* __restrict__ w, const float* __restrict__ bias,
                       float* __restrict__ out) {
  int id = blockIdx.x * blockDim.x + threadIdx.x;
  int b = id >> 9, j = id & 511;
  const float* wr = w + (size_t)j * 1024;
  const float* cr = cnn + (size_t)b * HIDD;
  const float* br = belief + (size_t)b * HIDD;
  float acc = bias[j];
  #pragma unroll 4
  for (int k = 0; k < HIDD; ++k) acc += cr[k] * wr[k];
  #pragma unroll 4
  for (int k = 0; k < HIDD; ++k) acc += br[k] * wr[512 + k];
  if (j < 256) out[O_MUPO + b * 256 + j] = acc;
  else         out[O_LVPO + b * 256 + (j - 256)] = acc;
}

__global__ void k_z(const float* __restrict__ eps, float* __restrict__ out) {
  int id = blockIdx.x * blockDim.x + threadIdx.x;  // B*256
  int b = id >> 8, i = id & 255;
  float mu = out[O_MUPO + b * 256 + i];
  float lv = out[O_LVPO + b * 256 + i];
  out[O_ZT + b * 256 + i] = mu + eps[id] * expf(0.5f * lv);
}

// ================= dec_fc : dec[m, b], z staged in LDS =================

__global__ __launch_bounds__(256) void k_decfc_bt(const float* __restrict__ z,
                                                  const float* __restrict__ w,
                                                  const float* __restrict__ bias,
                                                  float* __restrict__ dec) {
  __shared__ float zs[64 * 129];
  int tid = threadIdx.x;
  #pragma unroll
  for (int i = 0; i < 32; ++i) {
    int idx = tid + i * 256;          // 8192 = 64*128
    int b = idx >> 7, k = idx & 127;
    zs[b * 129 + k] = z[(size_t)b * 256 + k];
  }
  __syncthreads();
  int lane = tid & 63;
  int wq = tid >> 6;
  int m0 = blockIdx.x * 16 + wq * 4;
  float acc[4];
  #pragma unroll
  for (int mi = 0; mi < 4; ++mi) acc[mi] = bias[m0 + mi];
  for (int k = 0; k < 128; ++k) {
    float zv = zs[lane * 129 + k];
    #pragma unroll
    for (int mi = 0; mi < 4; ++mi) acc[mi] += zv * w[(size_t)(m0 + mi) * 128 + k];
  }
  #pragma unroll
  for (int mi = 0; mi < 4; ++mi) dec[(size_t)(m0 + mi) * 64 + lane] = acc[mi];
}

// ================= launch =================

extern "C" void kernel_launch(void* const* d_in, const int* in_sizes, int n_in,
                              void* d_out, int out_size, void* d_ws, size_t ws_size,
                              hipStream_t stream) {
  const float* img      = (const float*)d_in[0];
  const float* act      = (const float*)d_in[1];
  const float* z_prev   = (const float*)d_in[2];
  const float* st_prev  = (const float*)d_in[3];
  const float* eps      = (const float*)d_in[4];
  const float* c1w = (const float*)d_in[5];  const float* c1b = (const float*)d_in[6];
  const float* c2w = (const float*)d_in[7];  const float* c2b = (const float*)d_in[8];
  const float* c3w = (const float*)d_in[9];  const float* c3b = (const float*)d_in[10];
  const float* c4w = (const float*)d_in[11]; const float* c4b = (const float*)d_in[12];
  const float* efw = (const float*)d_in[13]; const float* efb = (const float*)d_in[14];
  const float* pow_ = (const float*)d_in[15]; const float* pob = (const float*)d_in[16];
  const float* prw = (const float*)d_in[17]; const float* prb = (const float*)d_in[18];
  const float* siw = (const float*)d_in[19]; const float* sib = (const float*)d_in[20];
  const float* Alog = (const float*)d_in[21];
  const float* Bw = (const float*)d_in[22];  const float* Cw = (const float*)d_in[23];
  const float* Dw = (const float*)d_in[24];  const float* Db = (const float*)d_in[25];
  const float* Dv = (const float*)d_in[26];
  const float* dfw = (const float*)d_in[27]; const float* dfb = (const float*)d_in[28];
  const float* d1w = (const float*)d_in[29]; const float* d1b = (const float*)d_in[30];
  const float* d2w = (const float*)d_in[31]; const float* d2b = (const float*)d_in[32];
  const float* d3w = (const float*)d_in[33]; const float* d3b = (const float*)d_in[34];
  const float* d4w = (const float*)d_in[35]; const float* d4b = (const float*)d_in[36];

  float* ws = (float*)d_ws;
  float* out = (float*)d_out;

  // ---- SSM chain ----
  k_ssm_in<<<128, 256, 0, stream>>>(z_prev, act, siw, sib, ws + W_SSMIN);
  k_delta<<<128, 256, 0, stream>>>(ws + W_SSMIN, Dw, Db, ws + W_DELTA);
  k_bc<<<4, 256, 0, stream>>>(ws + W_SSMIN, Bw, Cw, ws + W_BT, ws + W_CT);
  k_state<<<128, 256, 0, stream>>>(ws + W_DELTA, ws + W_SSMIN, Alog, ws + W_BT,
                                   ws + W_CT, Dv, st_prev, out + O_STATE, ws + W_BELIEF);
  k_prior<<<128, 256, 0, stream>>>(ws + W_BELIEF, prw, prb, out);

  // ---- img -> batch-inner layout ----
  k_timg<<<3072, 256, 0, stream>>>(img, ws + W_TIMG);

  // ---- encoder convs (batch-inner) ----
  conv_bt<4><<<8192, 256, 0, stream>>>(ws + W_TIMG, c1w, c1b, ws + W_H1, 3, 256, 256, 32, 128, 128);
  conv_bt<4><<<4096, 256, 0, stream>>>(ws + W_H1, c2w, c2b, ws + W_H2, 32, 128, 128, 64, 64, 64);
  conv_bt<4><<<2048, 256, 0, stream>>>(ws + W_H2, c3w, c3b, ws + W_H3, 64, 64, 64, 128, 32, 32);
  conv_bt<4><<<1024, 256, 0, stream>>>(ws + W_H3, c4w, c4b, ws + W_H4T, 128, 32, 32, 256, 16, 16);

  // ---- enc_fc (h4t is already [k,64]) ----
  k_encfc<<<(512 / ENC_OT) * ENC_NS, 64, 0, stream>>>(ws + W_H4T, efw, ws + W_ENCP);
  k_encfc_red<<<128, 256, 0, stream>>>(ws + W_ENCP, efb, ws + W_CNN);

  // ---- posterior + reparam ----
  k_post<<<128, 256, 0, stream>>>(ws + W_CNN, ws + W_BELIEF, pow_, pob, out);
  k_z<<<64, 256, 0, stream>>>(eps, out);

  // ---- decoder ----
  k_decfc_bt<<<2048, 256, 0, stream>>>(out + O_ZT, dfw, dfb, ws + W_DEC);
  deconv_bt<4, true><<<1024, 256, 0, stream>>>(ws + W_DEC, d1w, d1b, ws + W_D1, 128, 16, 16, 64, 32, 32);
  deconv_bt<4, true><<<2048, 256, 0, stream>>>(ws + W_D1, d2w, d2b, ws + W_D2, 64, 32, 32, 32, 64, 64);
  deconv_bt<4, true><<<4096, 256, 0, stream>>>(ws + W_D2, d3w, d3b, ws + W_D3, 32, 64, 64, 16, 128, 128);
  deconv_bt<1, false><<<4096, 256, 0, stream>>>(ws + W_D3, d4w, d4b, ws + W_PREDT, 16, 128, 128, 1, 256, 256);

  // ---- predT -> out layout ----
  k_tout<<<1024, 256, 0, stream>>>(ws + W_PREDT, out + O_PRED);
}

// Round 3
// 1953.673 us; speedup vs baseline: 16.8091x; 2.4752x over previous
//
#include <hip/hip_runtime.h>
#include <math.h>

#define BB 64
#define LATENT 256
#define ACTD 6
#define HIDD 512
#define DST 16

// ---------------- output offsets (floats) ----------------
#define O_PRED   0
#define O_ZT     4194304
#define O_STATE  4210688
#define O_MUP    4734976
#define O_LVP    4751360
#define O_MUPO   4767744
#define O_LVPO   4784128

// ---------------- ws offsets (floats), lifetime-reused ----------------
#define W_SSMIN  0u
#define W_DELTA  32768u
#define W_BT     65536u
#define W_CT     66560u
#define W_BELIEF 67584u
#define W_CNN    100352u
// big regions
#define W_H1     1181696u                 // 33,554,432  [1.18M .. 34.74M)
#define W_TIMG   34736128u                // 12,582,912  [34.74M .. 47.32M)
#define W_H2     47319040u                // 16,777,216  [47.32M .. 64.10M)
#define W_H3     1181696u                 // 8,388,608   reuse H1 (h1 dead)
#define W_H4T    9570304u                 // 4,194,304   reuse H1 tail
#define W_ENCP   34736128u                // 33,554,432? no: 512*256*64 = 8,388,608 floats, fits TIMG region
#define W_DEC    38930432u                // 2,097,152   TIMG region (after ENCP dead)
#define W_D1     41027584u                // 4,194,304   TIMG region
#define W_D2     47319040u                // 8,388,608   reuse H2
#define W_D3     1181696u                 // 16,777,216  reuse H1 (h3/h4t dead)
#define W_PREDT  38930432u                // 4,194,304   reuse DEC (dead)

#define ENC_KS 256

// ================= SSM / small dense =================

__global__ void k_ssm_in(const float* __restrict__ z_prev, const float* __restrict__ act,
                         const float* __restrict__ w, const float* __restrict__ bias,
                         float* __restrict__ out) {
  int id = blockIdx.x * blockDim.x + threadIdx.x;
  int b = id >> 9, h = id & 511;
  const float* wr = w + (size_t)h * (LATENT + ACTD);
  const float* zr = z_prev + (size_t)b * LATENT;
  float acc = bias[h];
  #pragma unroll 4
  for (int k = 0; k < LATENT; ++k) acc += zr[k] * wr[k];
  const float* ar = act + (size_t)b * ACTD;
  #pragma unroll
  for (int k = 0; k < ACTD; ++k) acc += ar[k] * wr[LATENT + k];
  out[id] = acc / (1.f + expf(-acc));   // silu
}

__global__ void k_delta(const float* __restrict__ ssm_in, const float* __restrict__ w,
                        const float* __restrict__ bias, float* __restrict__ out) {
  int id = blockIdx.x * blockDim.x + threadIdx.x;
  int b = id >> 9, h = id & 511;
  const float* xr = ssm_in + (size_t)b * HIDD;
  const float* wr = w + (size_t)h * HIDD;
  float acc = bias[h];
  #pragma unroll 4
  for (int k = 0; k < HIDD; ++k) acc += xr[k] * wr[k];
  out[id] = fmaxf(acc, 0.f) + log1pf(expf(-fabsf(acc)));  // stable softplus
}

__global__ void k_bc(const float* __restrict__ ssm_in, const float* __restrict__ Bw,
                     const float* __restrict__ Cw, float* __restrict__ Bt,
                     float* __restrict__ Ct) {
  int id = blockIdx.x * blockDim.x + threadIdx.x;   // B*16
  if (id >= BB * DST) return;
  int b = id >> 4, n = id & 15;
  const float* xr = ssm_in + (size_t)b * HIDD;
  const float* br = Bw + (size_t)n * HIDD;
  const float* cr = Cw + (size_t)n * HIDD;
  float ab = 0.f, ac = 0.f;
  #pragma unroll 4
  for (int k = 0; k < HIDD; ++k) { ab += xr[k] * br[k]; ac += xr[k] * cr[k]; }
  Bt[id] = ab; Ct[id] = ac;
}

__global__ void k_state(const float* __restrict__ Delta, const float* __restrict__ ssm_in,
                        const float* __restrict__ A_log, const float* __restrict__ Bt,
                        const float* __restrict__ Ct, const float* __restrict__ Dv,
                        const float* __restrict__ prev, float* __restrict__ state_out,
                        float* __restrict__ belief) {
  int id = blockIdx.x * blockDim.x + threadIdx.x;
  int b = id >> 9, h = id & 511;
  float d = Delta[id], si = ssm_in[id];
  float bel = Dv[h] * si;
  const float* al = A_log + (size_t)h * DST;
  const float* bt = Bt + (size_t)b * DST;
  const float* ct = Ct + (size_t)b * DST;
  const float* sp = prev + (size_t)id * DST;
  float* so = state_out + (size_t)id * DST;
  #pragma unroll
  for (int n = 0; n < DST; ++n) {
    float A = -expf(al[n]);
    float st = expf(d * A) * sp[n] + d * bt[n] * si;
    so[n] = st;
    bel += st * ct[n];
  }
  belief[id] = bel;
}

__global__ void k_prior(const float* __restrict__ belief, const float* __restrict__ w,
                        const float* __restrict__ bias, float* __restrict__ out) {
  int id = blockIdx.x * blockDim.x + threadIdx.x;
  int b = id >> 9, j = id & 511;
  const float* xr = belief + (size_t)b * HIDD;
  const float* wr = w + (size_t)j * HIDD;
  float acc = bias[j];
  #pragma unroll 4
  for (int k = 0; k < HIDD; ++k) acc += xr[k] * wr[k];
  if (j < 256) out[O_MUP + b * 256 + j] = acc;
  else         out[O_LVP + b * 256 + (j - 256)] = acc;
}

// ================= layout transposes =================
// img [B,3,256,256] -> timg [3, 65536, B]
__global__ __launch_bounds__(256) void k_timg(const float* __restrict__ img,
                                              float* __restrict__ timg) {
  int blk = blockIdx.x;
  int c = blk >> 10, p0 = (blk & 1023) << 6;
  __shared__ float t[64 * 65];
  int tid = threadIdx.x;
  #pragma unroll
  for (int i = 0; i < 16; ++i) {
    int idx = tid + i * 256;
    int b = idx >> 6, pr = idx & 63;
    t[pr * 65 + b] = img[((size_t)b * 3 + c) * 65536 + p0 + pr];
  }
  __syncthreads();
  #pragma unroll
  for (int i = 0; i < 16; ++i) {
    int idx = tid + i * 256;
    int pr = idx >> 6, b = idx & 63;
    timg[((size_t)c * 65536 + p0 + pr) * 64 + b] = t[pr * 65 + b];
  }
}

// predT [65536, B] -> out [B, 65536]
__global__ __launch_bounds__(256) void k_tout(const float* __restrict__ predT,
                                              float* __restrict__ out) {
  int p0 = blockIdx.x << 6;
  __shared__ float t[64 * 65];
  int tid = threadIdx.x;
  #pragma unroll
  for (int i = 0; i < 16; ++i) {
    int idx = tid + i * 256;
    int pr = idx >> 6, b = idx & 63;
    t[pr * 65 + b] = predT[(size_t)(p0 + pr) * 64 + b];
  }
  __syncthreads();
  #pragma unroll
  for (int i = 0; i < 16; ++i) {
    int idx = tid + i * 256;
    int b = idx >> 6, pr = idx & 63;
    out[(size_t)b * 65536 + p0 + pr] = t[pr * 65 + b];
  }
}

// ================= conv 4x4 s2 p1 + relu, batch-inner layout =================
template<int CT>
__global__ __launch_bounds__(256) void conv_bt(const float* __restrict__ in,
                                               const float* __restrict__ w,
                                               const float* __restrict__ bias,
                                               float* __restrict__ out,
                                               int Cin, int Hin, int Win,
                                               int Cout, int Hout, int Wout) {
  int wid = __builtin_amdgcn_readfirstlane(blockIdx.x * 4 + (threadIdx.x >> 6));
  int lane = threadIdx.x & 63;
  int nx4 = Wout >> 2;
  int x4 = wid % nx4; int t = wid / nx4;
  int oy = t % Hout; int cg = t / Hout;
  int co0 = cg * CT;
  if (co0 >= Cout) return;
  int ox0 = x4 << 2;
  int ixb = ox0 * 2 - 1;
  float acc[CT][4];
  #pragma unroll
  for (int u = 0; u < CT; ++u) {
    float bv = bias[co0 + u];
    #pragma unroll
    for (int j = 0; j < 4; ++j) acc[u][j] = bv;
  }
  for (int ci = 0; ci < Cin; ++ci) {
    const float* ip = in + ((size_t)ci * Hin * Win) * 64 + lane;
    const float* wp = w + ((size_t)co0 * Cin + ci) * 16;
    #pragma unroll
    for (int ky = 0; ky < 4; ++ky) {
      int iy = oy * 2 - 1 + ky;
      if ((unsigned)iy >= (unsigned)Hin) continue;
      const float* rp = ip + (size_t)iy * Win * 64;
      float x[10];
      #pragma unroll
      for (int j = 0; j < 10; ++j) {
        int ix = ixb + j;
        x[j] = ((unsigned)ix < (unsigned)Win) ? rp[(size_t)ix * 64] : 0.f;
      }
      #pragma unroll
      for (int u = 0; u < CT; ++u) {
        const float* wq = wp + (size_t)u * Cin * 16 + ky * 4;
        float w0 = wq[0], w1 = wq[1], w2 = wq[2], w3 = wq[3];
        acc[u][0] += x[0]*w0 + x[1]*w1 + x[2]*w2 + x[3]*w3;
        acc[u][1] += x[2]*w0 + x[3]*w1 + x[4]*w2 + x[5]*w3;
        acc[u][2] += x[4]*w0 + x[5]*w1 + x[6]*w2 + x[7]*w3;
        acc[u][3] += x[6]*w0 + x[7]*w1 + x[8]*w2 + x[9]*w3;
      }
    }
  }
  #pragma unroll
  for (int u = 0; u < CT; ++u) {
    size_t ob = (((size_t)(co0 + u) * Hout + oy) * Wout + ox0) * 64 + lane;
    #pragma unroll
    for (int j = 0; j < 4; ++j) out[ob + (size_t)j * 64] = fmaxf(acc[u][j], 0.f);
  }
}

// ================= transposed conv 4x4 s2 p1, batch-inner layout =================
template<int CT, bool RELU>
__global__ __launch_bounds__(256) void deconv_bt(const float* __restrict__ in,
                                                 const float* __restrict__ w,
                                                 const float* __restrict__ bias,
                                                 float* __restrict__ out,
                                                 int Cin, int Hin, int Win,
                                                 int Cout, int Hout, int Wout) {
  int wid = __builtin_amdgcn_readfirstlane(blockIdx.x * 4 + (threadIdx.x >> 6));
  int lane = threadIdx.x & 63;
  int nx4 = Wout >> 2;
  int x4 = wid % nx4; int t = wid / nx4;
  int oy = t % Hout; int cg = t / Hout;
  int co0 = cg * CT;
  if (co0 >= Cout) return;
  int ox0 = x4 << 2;
  int p0 = (oy + 1) & 1;
  int iy_hi = (oy + 1 - p0) >> 1;
  int iy_lo = iy_hi - 1;
  int ixb = (ox0 >> 1) - 1;
  float acc[CT][4];
  #pragma unroll
  for (int u = 0; u < CT; ++u) {
    float bv = bias[co0 + u];
    #pragma unroll
    for (int j = 0; j < 4; ++j) acc[u][j] = bv;
  }
  for (int ci = 0; ci < Cin; ++ci) {
    const float* ipb = in + ((size_t)ci * Hin * Win) * 64 + lane;
    const float* wcb = w + ((size_t)ci * Cout + co0) * 16;
    #pragma unroll
    for (int r = 0; r < 2; ++r) {
      int iy = r ? iy_hi : iy_lo;
      int p = r ? p0 : (p0 + 2);
      if ((unsigned)iy >= (unsigned)Hin) continue;
      const float* rp = ipb + (size_t)iy * Win * 64;
      float xv[4];
      #pragma unroll
      for (int i = 0; i < 4; ++i) {
        int ix = ixb + i;
        xv[i] = ((unsigned)ix < (unsigned)Win) ? rp[(size_t)ix * 64] : 0.f;
      }
      #pragma unroll
      for (int u = 0; u < CT; ++u) {
        const float* wq = wcb + (size_t)u * 16 + p * 4;
        float q0 = wq[0], q1 = wq[1], q2 = wq[2], q3 = wq[3];
        acc[u][0] += xv[1]*q1 + xv[0]*q3;
        acc[u][1] += xv[2]*q0 + xv[1]*q2;
        acc[u][2] += xv[2]*q1 + xv[1]*q3;
        acc[u][3] += xv[3]*q0 + xv[2]*q2;
      }
    }
  }
  #pragma unroll
  for (int u = 0; u < CT; ++u) {
    size_t ob = (((size_t)(co0 + u) * Hout + oy) * Wout + ox0) * 64 + lane;
    #pragma unroll
    for (int j = 0; j < 4; ++j) {
      float v = acc[u][j];
      if (RELU) v = fmaxf(v, 0.f);
      out[ob + (size_t)j * 64] = v;
    }
  }
}

// ================= enc_fc tiled GEMM =================
// hT (65536,64) @ W^T (512,65536) -> partial[n][ks][b]
// grid = 4 n-tiles x 256 k-splits; block 128 thr; tile M=64 N=128 Kc=256
__global__ __launch_bounds__(128) void k_encfc_gemm(const float* __restrict__ hT,
                                                    const float* __restrict__ w,
                                                    float* __restrict__ partial) {
  __shared__ float hts[32][68];
  __shared__ float wts[128][36];
  int bid = blockIdx.x;
  int nt = bid & 3;
  int ks = bid >> 2;
  int n0 = nt << 7;
  int k0 = ks << 8;
  int tid = threadIdx.x;
  int tx = tid & 7;          // batch group (8 batches)
  int ty = tid >> 3;         // n group (8 outputs)
  float acc[8][8];
  #pragma unroll
  for (int i = 0; i < 8; ++i)
    #pragma unroll
    for (int j = 0; j < 8; ++j) acc[i][j] = 0.f;

  for (int s = 0; s < 8; ++s) {
    int kb = k0 + s * 32;
    #pragma unroll
    for (int i = 0; i < 4; ++i) {
      int idx = tid + i * 128;
      int kk = idx >> 4, c4 = (idx & 15) << 2;
      *(float4*)&hts[kk][c4] = *(const float4*)&hT[(size_t)(kb + kk) * 64 + c4];
    }
    #pragma unroll
    for (int i = 0; i < 8; ++i) {
      int idx = tid + i * 128;
      int r = idx >> 3, c4 = (idx & 7) << 2;
      *(float4*)&wts[r][c4] = *(const float4*)&w[(size_t)(n0 + r) * 65536 + kb + c4];
    }
    __syncthreads();
    #pragma unroll
    for (int g = 0; g < 8; ++g) {
      int kg = g << 2;
      float4 av[4][2], bv[8];
      #pragma unroll
      for (int dk = 0; dk < 4; ++dk) {
        av[dk][0] = *(float4*)&hts[kg + dk][tx * 8];
        av[dk][1] = *(float4*)&hts[kg + dk][tx * 8 + 4];
      }
      #pragma unroll
      for (int j = 0; j < 8; ++j) bv[j] = *(float4*)&wts[ty * 8 + j][kg];
      #pragma unroll
      for (int dk = 0; dk < 4; ++dk) {
        #pragma unroll
        for (int j = 0; j < 8; ++j) {
          float wv = (dk == 0) ? bv[j].x : (dk == 1) ? bv[j].y : (dk == 2) ? bv[j].z : bv[j].w;
          #pragma unroll
          for (int h = 0; h < 2; ++h) {
            float4 a = av[dk][h];
            acc[h*4+0][j] += a.x * wv;
            acc[h*4+1][j] += a.y * wv;
            acc[h*4+2][j] += a.z * wv;
            acc[h*4+3][j] += a.w * wv;
          }
        }
      }
    }
    __syncthreads();
  }
  #pragma unroll
  for (int j = 0; j < 8; ++j) {
    int n = n0 + ty * 8 + j;
    #pragma unroll
    for (int i = 0; i < 8; ++i)
      partial[((size_t)n * ENC_KS + ks) * 64 + tx * 8 + i] = acc[i][j];
  }
}

__global__ void k_encfc_red(const float* __restrict__ partial, const float* __restrict__ bias,
                            float* __restrict__ cnn) {
  int id = blockIdx.x * blockDim.x + threadIdx.x;  // o*64 + b
  int o = id >> 6, b = id & 63;
  float acc = bias[o];
  #pragma unroll 8
  for (int s = 0; s < ENC_KS; ++s) acc += partial[((size_t)o * ENC_KS + s) * 64 + b];
  cnn[(size_t)b * 512 + o] = fmaxf(acc, 0.f);
}

// ================= posterior / reparam =================

__global__ void k_post(const float* __restrict__ cnn, const float* __restrict__ belief,
                       const float* __restrict__ w, const float* __restrict__ bias,
                       float* __restrict__ out) {
  int id = blockIdx.x * blockDim.x + threadIdx.x;
  int b = id >> 9, j = id & 511;
  const float* wr = w + (size_t)j * 1024;
  const float* cr = cnn + (size_t)b * HIDD;
  const float* br = belief + (size_t)b * HIDD;
  float acc = bias[j];
  #pragma unroll 4
  for (int k = 0; k < HIDD; ++k) acc += cr[k] * wr[k];
  #pragma unroll 4
  for (int k = 0; k < HIDD; ++k) acc += br[k] * wr[512 + k];
  if (j < 256) out[O_MUPO + b * 256 + j] = acc;
  else         out[O_LVPO + b * 256 + (j - 256)] = acc;
}

__global__ void k_z(const float* __restrict__ eps, float* __restrict__ out) {
  int id = blockIdx.x * blockDim.x + threadIdx.x;  // B*256
  int b = id >> 8, i = id & 255;
  float mu = out[O_MUPO + b * 256 + i];
  float lv = out[O_LVPO + b * 256 + i];
  out[O_ZT + b * 256 + i] = mu + eps[id] * expf(0.5f * lv);
}

// ================= dec_fc : dec[m, b], z staged in LDS =================

__global__ __launch_bounds__(256) void k_decfc_bt(const float* __restrict__ z,
                                                  const float* __restrict__ w,
                                                  const float* __restrict__ bias,
                                                  float* __restrict__ dec) {
  __shared__ float zs[64 * 129];
  int tid = threadIdx.x;
  #pragma unroll
  for (int i = 0; i < 32; ++i) {
    int idx = tid + i * 256;          // 8192 = 64*128
    int b = idx >> 7, k = idx & 127;
    zs[b * 129 + k] = z[(size_t)b * 256 + k];
  }
  __syncthreads();
  int lane = tid & 63;
  int wq = tid >> 6;
  int m0 = blockIdx.x * 16 + wq * 4;
  float acc[4];
  #pragma unroll
  for (int mi = 0; mi < 4; ++mi) acc[mi] = bias[m0 + mi];
  for (int k = 0; k < 128; ++k) {
    float zv = zs[lane * 129 + k];
    #pragma unroll
    for (int mi = 0; mi < 4; ++mi) acc[mi] += zv * w[(size_t)(m0 + mi) * 128 + k];
  }
  #pragma unroll
  for (int mi = 0; mi < 4; ++mi) dec[(size_t)(m0 + mi) * 64 + lane] = acc[mi];
}

// ================= launch =================

extern "C" void kernel_launch(void* const* d_in, const int* in_sizes, int n_in,
                              void* d_out, int out_size, void* d_ws, size_t ws_size,
                              hipStream_t stream) {
  const float* img      = (const float*)d_in[0];
  const float* act      = (const float*)d_in[1];
  const float* z_prev   = (const float*)d_in[2];
  const float* st_prev  = (const float*)d_in[3];
  const float* eps      = (const float*)d_in[4];
  const float* c1w = (const float*)d_in[5];  const float* c1b = (const float*)d_in[6];
  const float* c2w = (const float*)d_in[7];  const float* c2b = (const float*)d_in[8];
  const float* c3w = (const float*)d_in[9];  const float* c3b = (const float*)d_in[10];
  const float* c4w = (const float*)d_in[11]; const float* c4b = (const float*)d_in[12];
  const float* efw = (const float*)d_in[13]; const float* efb = (const float*)d_in[14];
  const float* pow_ = (const float*)d_in[15]; const float* pob = (const float*)d_in[16];
  const float* prw = (const float*)d_in[17]; const float* prb = (const float*)d_in[18];
  const float* siw = (const float*)d_in[19]; const float* sib = (const float*)d_in[20];
  const float* Alog = (const float*)d_in[21];
  const float* Bw = (const float*)d_in[22];  const float* Cw = (const float*)d_in[23];
  const float* Dw = (const float*)d_in[24];  const float* Db = (const float*)d_in[25];
  const float* Dv = (const float*)d_in[26];
  const float* dfw = (const float*)d_in[27]; const float* dfb = (const float*)d_in[28];
  const float* d1w = (const float*)d_in[29]; const float* d1b = (const float*)d_in[30];
  const float* d2w = (const float*)d_in[31]; const float* d2b = (const float*)d_in[32];
  const float* d3w = (const float*)d_in[33]; const float* d3b = (const float*)d_in[34];
  const float* d4w = (const float*)d_in[35]; const float* d4b = (const float*)d_in[36];

  float* ws = (float*)d_ws;
  float* out = (float*)d_out;

  // ---- SSM chain ----
  k_ssm_in<<<128, 256, 0, stream>>>(z_prev, act, siw, sib, ws + W_SSMIN);
  k_delta<<<128, 256, 0, stream>>>(ws + W_SSMIN, Dw, Db, ws + W_DELTA);
  k_bc<<<4, 256, 0, stream>>>(ws + W_SSMIN, Bw, Cw, ws + W_BT, ws + W_CT);
  k_state<<<128, 256, 0, stream>>>(ws + W_DELTA, ws + W_SSMIN, Alog, ws + W_BT,
                                   ws + W_CT, Dv, st_prev, out + O_STATE, ws + W_BELIEF);
  k_prior<<<128, 256, 0, stream>>>(ws + W_BELIEF, prw, prb, out);

  // ---- img -> batch-inner layout ----
  k_timg<<<3072, 256, 0, stream>>>(img, ws + W_TIMG);

  // ---- encoder convs (batch-inner, CT=8) ----
  conv_bt<8><<<4096, 256, 0, stream>>>(ws + W_TIMG, c1w, c1b, ws + W_H1, 3, 256, 256, 32, 128, 128);
  conv_bt<8><<<2048, 256, 0, stream>>>(ws + W_H1, c2w, c2b, ws + W_H2, 32, 128, 128, 64, 64, 64);
  conv_bt<8><<<1024, 256, 0, stream>>>(ws + W_H2, c3w, c3b, ws + W_H3, 64, 64, 64, 128, 32, 32);
  conv_bt<8><<<512, 256, 0, stream>>>(ws + W_H3, c4w, c4b, ws + W_H4T, 128, 32, 32, 256, 16, 16);

  // ---- enc_fc tiled GEMM ----
  k_encfc_gemm<<<4 * ENC_KS, 128, 0, stream>>>(ws + W_H4T, efw, ws + W_ENCP);
  k_encfc_red<<<128, 256, 0, stream>>>(ws + W_ENCP, efb, ws + W_CNN);

  // ---- posterior + reparam ----
  k_post<<<128, 256, 0, stream>>>(ws + W_CNN, ws + W_BELIEF, pow_, pob, out);
  k_z<<<64, 256, 0, stream>>>(eps, out);

  // ---- decoder ----
  k_decfc_bt<<<2048, 256, 0, stream>>>(out + O_ZT, dfw, dfb, ws + W_DEC);
  deconv_bt<4, true><<<1024, 256, 0, stream>>>(ws + W_DEC, d1w, d1b, ws + W_D1, 128, 16, 16, 64, 32, 32);
  deconv_bt<4, true><<<2048, 256, 0, stream>>>(ws + W_D1, d2w, d2b, ws + W_D2, 64, 32, 32, 32, 64, 64);
  deconv_bt<4, true><<<4096, 256, 0, stream>>>(ws + W_D2, d3w, d3b, ws + W_D3, 32, 64, 64, 16, 128, 128);
  deconv_bt<1, false><<<4096, 256, 0, stream>>>(ws + W_D3, d4w, d4b, ws + W_PREDT, 16, 128, 128, 1, 256, 256);

  // ---- predT -> out layout ----
  k_tout<<<1024, 256, 0, stream>>>(ws + W_PREDT, out + O_PRED);
}

// Round 4
// 779.933 us; speedup vs baseline: 42.1054x; 2.5049x over previous
//
#include <hip/hip_runtime.h>
#include <math.h>

#define BB 64
#define LATENT 256
#define ACTD 6
#define HIDD 512
#define DST 16

typedef __attribute__((ext_vector_type(8))) short bf16x8;
typedef __attribute__((ext_vector_type(4))) float f32x4;

static __device__ __forceinline__ ushort f2bf(float f) {
  unsigned u = __builtin_bit_cast(unsigned, f);
  unsigned r = (u + 0x7FFFu + ((u >> 16) & 1u)) >> 16;
  return (ushort)r;
}
static __device__ __forceinline__ float bf2f(ushort u) {
  return __builtin_bit_cast(float, ((unsigned)u) << 16);
}

// ---------------- output offsets (floats) ----------------
#define O_PRED   0
#define O_ZT     4194304
#define O_STATE  4210688
#define O_MUP    4734976
#define O_LVP    4751360
#define O_MUPO   4767744
#define O_LVPO   4784128

// ---------------- ws offsets (floats), lifetime-reused ----------------
#define W_SSMIN  0u
#define W_DELTA  32768u
#define W_BT     65536u
#define W_CT     66560u
#define W_BELIEF 67584u
#define W_CNN    100352u
#define W_ZB16   133120u      // 64*128 u16
#define W_DECB   137216u      // 32768 f32
#define PW_C2    172032u      // 32768 u16
#define PW_C3    188416u      // 131072 u16
#define PW_C4    253952u      // 524288 u16
#define PW_D1    516096u      // 131072 u16
#define PW_D2    581632u      // 32768 u16
#define PW_D3    598016u      // 8192 u16
#define W_ENCW   602112u      // 33,554,432 u16
#define W_DECW   17379328u    // 4,194,304 u16
#define W_TIMG   19476480u    // 12,582,912 f32   [dead after conv1]
#define W_H1B    32059392u    // 33,554,432 u16   [dead after conv2]
#define W_H2B    48836608u    // 16,777,216 u16
#define W_H3B    57225216u    // 8,388,608 u16
#define W_H4B    61419520u    // 4,194,304 u16
// reuse of TIMG/H1B regions (dead by the time these are written):
#define W_ENCP   19476480u    // 512*128*64 f32
#define W_DECO   23670784u    // 2,097,152 u16
#define W_D1O    24719360u    // 4,194,304 u16
#define W_D2O    26816512u    // 8,388,608 u16
#define W_D3O    31010816u    // 16,777,216 u16 (spills into dead H1B)
#define W_PREDT  39399424u    // 4,194,304 f32

#define ENC_KS 128

// ================= SSM / small dense =================

__global__ void k_ssm_in(const float* __restrict__ z_prev, const float* __restrict__ act,
                         const float* __restrict__ w, const float* __restrict__ bias,
                         float* __restrict__ out) {
  int id = blockIdx.x * blockDim.x + threadIdx.x;
  int b = id >> 9, h = id & 511;
  const float* wr = w + (size_t)h * (LATENT + ACTD);
  const float* zr = z_prev + (size_t)b * LATENT;
  float acc = bias[h];
  #pragma unroll 4
  for (int k = 0; k < LATENT; ++k) acc += zr[k] * wr[k];
  const float* ar = act + (size_t)b * ACTD;
  #pragma unroll
  for (int k = 0; k < ACTD; ++k) acc += ar[k] * wr[LATENT + k];
  out[id] = acc / (1.f + expf(-acc));
}

__global__ void k_delta(const float* __restrict__ ssm_in, const float* __restrict__ w,
                        const float* __restrict__ bias, float* __restrict__ out) {
  int id = blockIdx.x * blockDim.x + threadIdx.x;
  int b = id >> 9, h = id & 511;
  const float* xr = ssm_in + (size_t)b * HIDD;
  const float* wr = w + (size_t)h * HIDD;
  float acc = bias[h];
  #pragma unroll 4
  for (int k = 0; k < HIDD; ++k) acc += xr[k] * wr[k];
  out[id] = fmaxf(acc, 0.f) + log1pf(expf(-fabsf(acc)));
}

__global__ void k_bc(const float* __restrict__ ssm_in, const float* __restrict__ Bw,
                     const float* __restrict__ Cw, float* __restrict__ Bt,
                     float* __restrict__ Ct) {
  int id = blockIdx.x * blockDim.x + threadIdx.x;
  if (id >= BB * DST) return;
  int b = id >> 4, n = id & 15;
  const float* xr = ssm_in + (size_t)b * HIDD;
  const float* br = Bw + (size_t)n * HIDD;
  const float* cr = Cw + (size_t)n * HIDD;
  float ab = 0.f, ac = 0.f;
  #pragma unroll 4
  for (int k = 0; k < HIDD; ++k) { ab += xr[k] * br[k]; ac += xr[k] * cr[k]; }
  Bt[id] = ab; Ct[id] = ac;
}

__global__ void k_state(const float* __restrict__ Delta, const float* __restrict__ ssm_in,
                        const float* __restrict__ A_log, const float* __restrict__ Bt,
                        const float* __restrict__ Ct, const float* __restrict__ Dv,
                        const float* __restrict__ prev, float* __restrict__ state_out,
                        float* __restrict__ belief) {
  int id = blockIdx.x * blockDim.x + threadIdx.x;
  int b = id >> 9, h = id & 511;
  float d = Delta[id], si = ssm_in[id];
  float bel = Dv[h] * si;
  const float* al = A_log + (size_t)h * DST;
  const float* bt = Bt + (size_t)b * DST;
  const float* ct = Ct + (size_t)b * DST;
  const float* sp = prev + (size_t)id * DST;
  float* so = state_out + (size_t)id * DST;
  #pragma unroll
  for (int n = 0; n < DST; ++n) {
    float A = -expf(al[n]);
    float st = expf(d * A) * sp[n] + d * bt[n] * si;
    so[n] = st;
    bel += st * ct[n];
  }
  belief[id] = bel;
}

__global__ void k_prior(const float* __restrict__ belief, const float* __restrict__ w,
                        const float* __restrict__ bias, float* __restrict__ out) {
  int id = blockIdx.x * blockDim.x + threadIdx.x;
  int b = id >> 9, j = id & 511;
  const float* xr = belief + (size_t)b * HIDD;
  const float* wr = w + (size_t)j * HIDD;
  float acc = bias[j];
  #pragma unroll 4
  for (int k = 0; k < HIDD; ++k) acc += xr[k] * wr[k];
  if (j < 256) out[O_MUP + b * 256 + j] = acc;
  else         out[O_LVP + b * 256 + (j - 256)] = acc;
}

// ================= weight prepacks =================
// conv w [Cout][Cin][4][4] f32 -> [Cout][(ky*4+kx)*Cin+ci] bf16
__global__ void k_pack_convw(const float* __restrict__ w, ushort* __restrict__ o,
                             int Cout, int Cin, int n) {
  int id = blockIdx.x * blockDim.x + threadIdx.x;
  if (id >= n) return;
  int kt = Cin * 16;
  int co = id / kt, r = id % kt;
  int tap = r / Cin, ci = r % Cin;
  o[id] = f2bf(w[(size_t)(co * Cin + ci) * 16 + tap]);
}

// deconv w [Cin][Cout][4][4] f32 -> [cls][Cout][t*Cin+ci] bf16, t=(i*2+j), p=p0+2i, q=q0+2j
__global__ void k_pack_deconvw(const float* __restrict__ w, ushort* __restrict__ o,
                               int Cout, int Cin, int n) {
  int id = blockIdx.x * blockDim.x + threadIdx.x;
  if (id >= n) return;
  int per = Cout * 4 * Cin;
  int cls = id / per, r1 = id % per;
  int co = r1 / (4 * Cin), r2 = r1 % (4 * Cin);
  int t = r2 / Cin, ci = r2 % Cin;
  int p = (cls >> 1) + 2 * (t >> 1);
  int q = (cls & 1) + 2 * (t & 1);
  o[id] = f2bf(w[(size_t)(ci * Cout + co) * 16 + p * 4 + q]);
}

// enc w [512][ci*256+px] f32 -> [512][px*256+ci] bf16 (LDS transpose per 64ci x 256px slab)
__global__ __launch_bounds__(256) void k_pack_encw(const float* __restrict__ w,
                                                   ushort* __restrict__ o) {
  __shared__ ushort lds[256][66];
  int bid = blockIdx.x;
  int ou = bid >> 2, ci0 = (bid & 3) << 6;
  int tid = threadIdx.x;
  const float* base = w + (size_t)ou * 65536;
  #pragma unroll 4
  for (int i = 0; i < 64; ++i) {
    int idx = tid + i * 256;
    int c = idx >> 8, px = idx & 255;
    lds[px][c] = f2bf(base[(size_t)(ci0 + c) * 256 + px]);
  }
  __syncthreads();
  ushort* ob = o + (size_t)ou * 65536 + ci0;
  #pragma unroll 4
  for (int i = 0; i < 64; ++i) {
    int idx = tid + i * 256;
    int px = idx >> 6, c = idx & 63;
    ob[(size_t)px * 256 + c] = lds[px][c];
  }
}

// dec w [co*256+pix][128] f32 -> [pix*128+co][128] bf16
__global__ void k_pack_decw(const float* __restrict__ w, ushort* __restrict__ o) {
  int id = blockIdx.x * blockDim.x + threadIdx.x;   // 4,194,304
  int m = id >> 7, k = id & 127;
  int pix = m >> 7, co = m & 127;
  o[id] = f2bf(w[(size_t)(co * 256 + pix) * 128 + k]);
}

__global__ void k_pack_decb(const float* __restrict__ b, float* __restrict__ o) {
  int id = blockIdx.x * blockDim.x + threadIdx.x;   // 32768
  int pix = id >> 7, co = id & 127;
  o[id] = b[co * 256 + pix];
}

// ================= layout transposes =================
// img [B,3,256,256] -> timg [3, 65536, B] f32
__global__ __launch_bounds__(256) void k_timg(const float* __restrict__ img,
                                              float* __restrict__ timg) {
  int blk = blockIdx.x;
  int c = blk >> 10, p0 = (blk & 1023) << 6;
  __shared__ float t[64 * 65];
  int tid = threadIdx.x;
  #pragma unroll
  for (int i = 0; i < 16; ++i) {
    int idx = tid + i * 256;
    int b = idx >> 6, pr = idx & 63;
    t[pr * 65 + b] = img[((size_t)b * 3 + c) * 65536 + p0 + pr];
  }
  __syncthreads();
  #pragma unroll
  for (int i = 0; i < 16; ++i) {
    int idx = tid + i * 256;
    int pr = idx >> 6, b = idx & 63;
    timg[((size_t)c * 65536 + p0 + pr) * 64 + b] = t[pr * 65 + b];
  }
}

// predT [65536, B] f32 -> out [B, 65536]
__global__ __launch_bounds__(256) void k_tout(const float* __restrict__ predT,
                                              float* __restrict__ out) {
  int p0 = blockIdx.x << 6;
  __shared__ float t[64 * 65];
  int tid = threadIdx.x;
  #pragma unroll
  for (int i = 0; i < 16; ++i) {
    int idx = tid + i * 256;
    int pr = idx >> 6, b = idx & 63;
    t[pr * 65 + b] = predT[(size_t)(p0 + pr) * 64 + b];
  }
  __syncthreads();
  #pragma unroll
  for (int i = 0; i < 16; ++i) {
    int idx = tid + i * 256;
    int b = idx >> 6, pr = idx & 63;
    out[(size_t)b * 65536 + p0 + pr] = t[pr * 65 + b];
  }
}

// ================= conv1: f32 direct (Cin=3), bf16 channel-inner out =================
// in timg [3][65536][64] f32; out h1b [128][128][64][32] bf16
__global__ __launch_bounds__(256) void k_conv1(const float* __restrict__ in,
                                               const float* __restrict__ w,
                                               const float* __restrict__ bias,
                                               ushort* __restrict__ out) {
  int wid = __builtin_amdgcn_readfirstlane(blockIdx.x * 4 + (threadIdx.x >> 6));
  int lane = threadIdx.x & 63;
  int x4 = wid & 31; int t = wid >> 5;
  int oy = t & 127; int cg = t >> 7;      // cg 0..3
  int co0 = cg * 8;
  int ox0 = x4 << 2;
  int ixb = ox0 * 2 - 1;
  float acc[8][4];
  #pragma unroll
  for (int u = 0; u < 8; ++u) {
    float bv = bias[co0 + u];
    #pragma unroll
    for (int j = 0; j < 4; ++j) acc[u][j] = bv;
  }
  for (int ci = 0; ci < 3; ++ci) {
    const float* ip = in + ((size_t)ci * 65536) * 64 + lane;
    const float* wp = w + (size_t)co0 * 48 + ci * 16;
    #pragma unroll
    for (int ky = 0; ky < 4; ++ky) {
      int iy = oy * 2 - 1 + ky;
      if ((unsigned)iy >= 256u) continue;
      const float* rp = ip + (size_t)iy * 256 * 64;
      float x[10];
      #pragma unroll
      for (int j = 0; j < 10; ++j) {
        int ix = ixb + j;
        x[j] = ((unsigned)ix < 256u) ? rp[(size_t)ix * 64] : 0.f;
      }
      #pragma unroll
      for (int u = 0; u < 8; ++u) {
        const float* wq = wp + (size_t)u * 48 + ky * 4;
        float w0 = wq[0], w1 = wq[1], w2 = wq[2], w3 = wq[3];
        acc[u][0] += x[0]*w0 + x[1]*w1 + x[2]*w2 + x[3]*w3;
        acc[u][1] += x[2]*w0 + x[3]*w1 + x[4]*w2 + x[5]*w3;
        acc[u][2] += x[4]*w0 + x[5]*w1 + x[6]*w2 + x[7]*w3;
        acc[u][3] += x[6]*w0 + x[7]*w1 + x[8]*w2 + x[9]*w3;
      }
    }
  }
  #pragma unroll
  for (int j = 0; j < 4; ++j) {
    size_t base = ((size_t)(oy * 128 + ox0 + j) * 64 + lane) * 32 + co0;
    #pragma unroll
    for (int u = 0; u < 8; u += 2) {
      unsigned pk = (unsigned)f2bf(fmaxf(acc[u][j], 0.f)) |
                    ((unsigned)f2bf(fmaxf(acc[u+1][j], 0.f)) << 16);
      *(unsigned*)(out + base + u) = pk;
    }
  }
}

// ================= MFMA conv 4x4 s2 p1 + relu =================
// in bf16 [Hin][Win][64][CIN]; wp bf16 [COUT][16*CIN]; out bf16 [Hout][Wout][64][COUT]
template<int CIN, int COUT, int MT>
__global__ __launch_bounds__(256) void mfma_conv(const ushort* __restrict__ in,
                                                 const ushort* __restrict__ wp,
                                                 const float* __restrict__ bias,
                                                 ushort* __restrict__ out,
                                                 int Hin, int Win, int Hout, int Wout) {
  constexpr int NMG = COUT / (16 * MT);
  constexpr int KTOT = 16 * CIN;
  int wid = __builtin_amdgcn_readfirstlane(blockIdx.x * 4 + (threadIdx.x >> 6));
  int lane = threadIdx.x & 63;
  int mg = wid % NMG;
  int px = wid / NMG;
  int ox = px % Wout, oy = px / Wout;
  if (oy >= Hout) return;
  int co0 = mg * 16 * MT;
  int ml = lane & 15, kl = (lane >> 4) * 8;
  f32x4 zero = {0.f, 0.f, 0.f, 0.f};
  f32x4 acc[MT][4];
  #pragma unroll
  for (int mt = 0; mt < MT; ++mt)
    #pragma unroll
    for (int nt = 0; nt < 4; ++nt) acc[mt][nt] = zero;

  for (int ky = 0; ky < 4; ++ky) {
    int iy = 2 * oy - 1 + ky;
    if ((unsigned)iy >= (unsigned)Hin) continue;
    for (int kx = 0; kx < 4; ++kx) {
      int ix = 2 * ox - 1 + kx;
      if ((unsigned)ix >= (unsigned)Win) continue;
      const ushort* ib = in + ((size_t)(iy * Win + ix) * 64) * CIN;
      int kt = (ky * 4 + kx) * CIN;
      #pragma unroll
      for (int kc = 0; kc < CIN / 32; ++kc) {
        int k = kt + kc * 32 + kl;
        bf16x8 a[MT], bb[4];
        #pragma unroll
        for (int mt = 0; mt < MT; ++mt)
          a[mt] = *(const bf16x8*)(wp + (size_t)(co0 + mt * 16 + ml) * KTOT + k);
        #pragma unroll
        for (int nt = 0; nt < 4; ++nt)
          bb[nt] = *(const bf16x8*)(ib + (size_t)(nt * 16 + ml) * CIN + kc * 32 + kl);
        #pragma unroll
        for (int mt = 0; mt < MT; ++mt)
          #pragma unroll
          for (int nt = 0; nt < 4; ++nt)
            acc[mt][nt] = __builtin_amdgcn_mfma_f32_16x16x32_bf16(a[mt], bb[nt], acc[mt][nt], 0, 0, 0);
      }
    }
  }
  int rb = (lane >> 4) * 4;
  #pragma unroll
  for (int mt = 0; mt < MT; ++mt) {
    int co = co0 + mt * 16 + rb;
    f32x4 bv = *(const f32x4*)(bias + co);
    #pragma unroll
    for (int nt = 0; nt < 4; ++nt) {
      int b = nt * 16 + ml;
      float v0 = fmaxf(acc[mt][nt][0] + bv[0], 0.f);
      float v1 = fmaxf(acc[mt][nt][1] + bv[1], 0.f);
      float v2 = fmaxf(acc[mt][nt][2] + bv[2], 0.f);
      float v3 = fmaxf(acc[mt][nt][3] + bv[3], 0.f);
      uint2 pk;
      pk.x = (unsigned)f2bf(v0) | ((unsigned)f2bf(v1) << 16);
      pk.y = (unsigned)f2bf(v2) | ((unsigned)f2bf(v3) << 16);
      *(uint2*)(out + ((size_t)px * 64 + b) * COUT + co) = pk;
    }
  }
}

// ================= MFMA transposed conv 4x4 s2 p1 + relu =================
// in bf16 [Hin][Win][64][CIN]; wp bf16 [cls][COUT][4*CIN]; out bf16 [Hout][Wout][64][COUT]
template<int CIN, int COUT, int MT>
__global__ __launch_bounds__(256) void mfma_deconv(const ushort* __restrict__ in,
                                                   const ushort* __restrict__ wp,
                                                   const float* __restrict__ bias,
                                                   ushort* __restrict__ out,
                                                   int Hin, int Win, int Hout, int Wout) {
  constexpr int NMG = COUT / (16 * MT);
  constexpr int KT = 4 * CIN;
  int wid = __builtin_amdgcn_readfirstlane(blockIdx.x * 4 + (threadIdx.x >> 6));
  int lane = threadIdx.x & 63;
  int mg = wid % NMG; int r1 = wid / NMG;
  int wo2 = Wout >> 1;
  int pc = (Hout >> 1) * wo2;
  int pxc = r1 % pc; int cls = r1 / pc;
  if (cls >= 4) return;
  int p0 = cls >> 1, q0 = cls & 1;
  int tx = pxc % wo2, ty = pxc / wo2;
  int oy = 2 * ty + 1 - p0, ox = 2 * tx + 1 - q0;
  int iy0 = (oy + 1 - p0) >> 1, ix0 = (ox + 1 - q0) >> 1;
  int co0 = mg * 16 * MT;
  int ml = lane & 15, kl = (lane >> 4) * 8;
  const ushort* wb = wp + (size_t)cls * COUT * KT;
  f32x4 zero = {0.f, 0.f, 0.f, 0.f};
  f32x4 acc[MT][4];
  #pragma unroll
  for (int mt = 0; mt < MT; ++mt)
    #pragma unroll
    for (int nt = 0; nt < 4; ++nt) acc[mt][nt] = zero;

  for (int i = 0; i < 2; ++i) {
    int iy = iy0 - i;
    if ((unsigned)iy >= (unsigned)Hin) continue;
    for (int j = 0; j < 2; ++j) {
      int ix = ix0 - j;
      if ((unsigned)ix >= (unsigned)Win) continue;
      const ushort* ib = in + ((size_t)(iy * Win + ix) * 64) * CIN;
      int kt = (i * 2 + j) * CIN;
      #pragma unroll
      for (int kc = 0; kc < CIN / 32; ++kc) {
        int k = kt + kc * 32 + kl;
        bf16x8 a[MT], bb[4];
        #pragma unroll
        for (int mt = 0; mt < MT; ++mt)
          a[mt] = *(const bf16x8*)(wb + (size_t)(co0 + mt * 16 + ml) * KT + k);
        #pragma unroll
        for (int nt = 0; nt < 4; ++nt)
          bb[nt] = *(const bf16x8*)(ib + (size_t)(nt * 16 + ml) * CIN + kc * 32 + kl);
        #pragma unroll
        for (int mt = 0; mt < MT; ++mt)
          #pragma unroll
          for (int nt = 0; nt < 4; ++nt)
            acc[mt][nt] = __builtin_amdgcn_mfma_f32_16x16x32_bf16(a[mt], bb[nt], acc[mt][nt], 0, 0, 0);
      }
    }
  }
  int rb = (lane >> 4) * 4;
  int px = oy * Wout + ox;
  #pragma unroll
  for (int mt = 0; mt < MT; ++mt) {
    int co = co0 + mt * 16 + rb;
    f32x4 bv = *(const f32x4*)(bias + co);
    #pragma unroll
    for (int nt = 0; nt < 4; ++nt) {
      int b = nt * 16 + ml;
      float v0 = fmaxf(acc[mt][nt][0] + bv[0], 0.f);
      float v1 = fmaxf(acc[mt][nt][1] + bv[1], 0.f);
      float v2 = fmaxf(acc[mt][nt][2] + bv[2], 0.f);
      float v3 = fmaxf(acc[mt][nt][3] + bv[3], 0.f);
      uint2 pk;
      pk.x = (unsigned)f2bf(v0) | ((unsigned)f2bf(v1) << 16);
      pk.y = (unsigned)f2bf(v2) | ((unsigned)f2bf(v3) << 16);
      *(uint2*)(out + ((size_t)px * 64 + b) * COUT + co) = pk;
    }
  }
}

// ================= enc_fc MFMA: partial[co][ks][b] =================
// h4 bf16 [256px][64b][256ci]; wE bf16 [512][k=px*256+ci]
__global__ __launch_bounds__(256) void k_encfc_mfma(const ushort* __restrict__ h4,
                                                    const ushort* __restrict__ wE,
                                                    float* __restrict__ partial) {
  int wid = __builtin_amdgcn_readfirstlane(blockIdx.x * 4 + (threadIdx.x >> 6)); // 0..2047
  int lane = threadIdx.x & 63;
  int mg = wid & 15, ks = wid >> 4;       // mg: 32-co group; ks: 0..127
  int co0 = mg * 32;
  int ml = lane & 15, kl = (lane >> 4) * 8;
  int k0 = ks * 512;
  f32x4 zero = {0.f, 0.f, 0.f, 0.f};
  f32x4 acc[2][4];
  #pragma unroll
  for (int mt = 0; mt < 2; ++mt)
    #pragma unroll
    for (int nt = 0; nt < 4; ++nt) acc[mt][nt] = zero;
  #pragma unroll 2
  for (int kc = 0; kc < 16; ++kc) {
    int k = k0 + kc * 32;
    int px = k >> 8, ci = k & 255;
    bf16x8 a[2], bb[4];
    #pragma unroll
    for (int mt = 0; mt < 2; ++mt)
      a[mt] = *(const bf16x8*)(wE + (size_t)(co0 + mt * 16 + ml) * 65536 + k + kl);
    #pragma unroll
    for (int nt = 0; nt < 4; ++nt)
      bb[nt] = *(const bf16x8*)(h4 + ((size_t)px * 64 + nt * 16 + ml) * 256 + ci + kl);
    #pragma unroll
    for (int mt = 0; mt < 2; ++mt)
      #pragma unroll
      for (int nt = 0; nt < 4; ++nt)
        acc[mt][nt] = __builtin_amdgcn_mfma_f32_16x16x32_bf16(a[mt], bb[nt], acc[mt][nt], 0, 0, 0);
  }
  int rb = (lane >> 4) * 4;
  #pragma unroll
  for (int mt = 0; mt < 2; ++mt) {
    int co = co0 + mt * 16 + rb;
    #pragma unroll
    for (int nt = 0; nt < 4; ++nt) {
      int b = nt * 16 + ml;
      #pragma unroll
      for (int r = 0; r < 4; ++r)
        partial[((size_t)(co + r) * ENC_KS + ks) * 64 + b] = acc[mt][nt][r];
    }
  }
}

__global__ void k_encfc_red(const float* __restrict__ partial, const float* __restrict__ bias,
                            float* __restrict__ cnn) {
  int id = blockIdx.x * blockDim.x + threadIdx.x;  // o*64 + b
  int o = id >> 6, b = id & 63;
  float acc = bias[o];
  #pragma unroll 8
  for (int s = 0; s < ENC_KS; ++s) acc += partial[((size_t)o * ENC_KS + s) * 64 + b];
  cnn[(size_t)b * 512 + o] = fmaxf(acc, 0.f);
}

// ================= posterior / reparam =================

__global__ void k_post(const float* __restrict__ cnn, const float* __restrict__ belief,
                       const float* __restrict__ w, const float* __restrict__ bias,
                       float* __restrict__ out) {
  int id = blockIdx.x * blockDim.x + threadIdx.x;
  int b = id >> 9, j = id & 511;
  const float* wr = w + (size_t)j * 1024;
  const float* cr = cnn + (size_t)b * HIDD;
  const float* br = belief + (size_t)b * HIDD;
  float acc = bias[j];
  #pragma unroll 4
  for (int k = 0; k < HIDD; ++k) acc += cr[k] * wr[k];
  #pragma unroll 4
  for (int k = 0; k < HIDD; ++k) acc += br[k] * wr[512 + k];
  if (j < 256) out[O_MUPO + b * 256 + j] = acc;
  else         out[O_LVPO + b * 256 + (j - 256)] = acc;
}

__global__ void k_z(const float* __restrict__ eps, float* __restrict__ out,
                    ushort* __restrict__ zb) {
  int id = blockIdx.x * blockDim.x + threadIdx.x;  // B*256
  int b = id >> 8, i = id & 255;
  float mu = out[O_MUPO + b * 256 + i];
  float lv = out[O_LVPO + b * 256 + i];
  float z = mu + eps[id] * expf(0.5f * lv);
  out[O_ZT + b * 256 + i] = z;
  if (i < 128) zb[b * 128 + i] = f2bf(z);
}

// ================= dec_fc MFMA =================
// zb bf16 [64][128]; wD bf16 [m=pix*128+co][128]; bD f32 [m]; dec bf16 [pix][64][128]
__global__ __launch_bounds__(256) void k_decfc_mfma(const ushort* __restrict__ zb,
                                                    const ushort* __restrict__ wD,
                                                    const float* __restrict__ bD,
                                                    ushort* __restrict__ dec) {
  int wid = __builtin_amdgcn_readfirstlane(blockIdx.x * 4 + (threadIdx.x >> 6)); // 0..1023
  int lane = threadIdx.x & 63;
  int m0 = wid * 32;
  int ml = lane & 15, kl = (lane >> 4) * 8;
  f32x4 zero = {0.f, 0.f, 0.f, 0.f};
  f32x4 acc[2][4];
  #pragma unroll
  for (int mt = 0; mt < 2; ++mt)
    #pragma unroll
    for (int nt = 0; nt < 4; ++nt) acc[mt][nt] = zero;
  #pragma unroll
  for (int kc = 0; kc < 4; ++kc) {
    bf16x8 a[2], bb[4];
    #pragma unroll
    for (int mt = 0; mt < 2; ++mt)
      a[mt] = *(const bf16x8*)(wD + (size_t)(m0 + mt * 16 + ml) * 128 + kc * 32 + kl);
    #pragma unroll
    for (int nt = 0; nt < 4; ++nt)
      bb[nt] = *(const bf16x8*)(zb + (size_t)(nt * 16 + ml) * 128 + kc * 32 + kl);
    #pragma unroll
    for (int mt = 0; mt < 2; ++mt)
      #pragma unroll
      for (int nt = 0; nt < 4; ++nt)
        acc[mt][nt] = __builtin_amdgcn_mfma_f32_16x16x32_bf16(a[mt], bb[nt], acc[mt][nt], 0, 0, 0);
  }
  int rb = (lane >> 4) * 4;
  #pragma unroll
  for (int mt = 0; mt < 2; ++mt) {
    int m = m0 + mt * 16 + rb;
    f32x4 bv = *(const f32x4*)(bD + m);
    int pix = m >> 7, co = m & 127;
    #pragma unroll
    for (int nt = 0; nt < 4; ++nt) {
      int b = nt * 16 + ml;
      uint2 pk;
      pk.x = (unsigned)f2bf(acc[mt][nt][0] + bv[0]) | ((unsigned)f2bf(acc[mt][nt][1] + bv[1]) << 16);
      pk.y = (unsigned)f2bf(acc[mt][nt][2] + bv[2]) | ((unsigned)f2bf(acc[mt][nt][3] + bv[3]) << 16);
      *(uint2*)(dec + ((size_t)pix * 64 + b) * 128 + co) = pk;
    }
  }
}

// ================= d4: direct deconv, Cout=1 =================
// in bf16 [128][128][64][16]; w f32 [16][1][4][4]; predT f32 [65536][64]
__global__ __launch_bounds__(256) void k_d4(const ushort* __restrict__ in,
                                            const float* __restrict__ w,
                                            const float* __restrict__ bias,
                                            float* __restrict__ predT) {
  int id = blockIdx.x * 256 + threadIdx.x;   // 4,194,304
  int b = id & 63; int px = id >> 6;
  int ox = px & 255, oy = px >> 8;
  int p0 = (oy + 1) & 1, q0 = (ox + 1) & 1;
  int iy0 = (oy + 1 - p0) >> 1, ix0 = (ox + 1 - q0) >> 1;
  float acc = bias[0];
  #pragma unroll
  for (int i = 0; i < 2; ++i) {
    int iy = iy0 - i;
    if ((unsigned)iy >= 128u) continue;
    int p = p0 + 2 * i;
    #pragma unroll
    for (int j = 0; j < 2; ++j) {
      int ix = ix0 - j;
      if ((unsigned)ix >= 128u) continue;
      int q = q0 + 2 * j;
      const ushort* ib = in + (((size_t)(iy * 128 + ix) * 64) + b) * 16;
      #pragma unroll
      for (int ci = 0; ci < 16; ++ci)
        acc += bf2f(ib[ci]) * w[ci * 16 + p * 4 + q];
    }
  }
  predT[id] = acc;
}

// ================= launch =================

extern "C" void kernel_launch(void* const* d_in, const int* in_sizes, int n_in,
                              void* d_out, int out_size, void* d_ws, size_t ws_size,
                              hipStream_t stream) {
  const float* img      = (const float*)d_in[0];
  const float* act      = (const float*)d_in[1];
  const float* z_prev   = (const float*)d_in[2];
  const float* st_prev  = (const float*)d_in[3];
  const float* eps      = (const float*)d_in[4];
  const float* c1w = (const float*)d_in[5];  const float* c1b = (const float*)d_in[6];
  const float* c2w = (const float*)d_in[7];  const float* c2b = (const float*)d_in[8];
  const float* c3w = (const float*)d_in[9];  const float* c3b = (const float*)d_in[10];
  const float* c4w = (const float*)d_in[11]; const float* c4b = (const float*)d_in[12];
  const float* efw = (const float*)d_in[13]; const float* efb = (const float*)d_in[14];
  const float* pow_ = (const float*)d_in[15]; const float* pob = (const float*)d_in[16];
  const float* prw = (const float*)d_in[17]; const float* prb = (const float*)d_in[18];
  const float* siw = (const float*)d_in[19]; const float* sib = (const float*)d_in[20];
  const float* Alog = (const float*)d_in[21];
  const float* Bw = (const float*)d_in[22];  const float* Cw = (const float*)d_in[23];
  const float* Dw = (const float*)d_in[24];  const float* Db = (const float*)d_in[25];
  const float* Dv = (const float*)d_in[26];
  const float* dfw = (const float*)d_in[27]; const float* dfb = (const float*)d_in[28];
  const float* d1w = (const float*)d_in[29]; const float* d1b = (const float*)d_in[30];
  const float* d2w = (const float*)d_in[31]; const float* d2b = (const float*)d_in[32];
  const float* d3w = (const float*)d_in[33]; const float* d3b = (const float*)d_in[34];
  const float* d4w = (const float*)d_in[35]; const float* d4b = (const float*)d_in[36];

  float* ws = (float*)d_ws;
  float* out = (float*)d_out;

  ushort* pc2 = (ushort*)(ws + PW_C2);
  ushort* pc3 = (ushort*)(ws + PW_C3);
  ushort* pc4 = (ushort*)(ws + PW_C4);
  ushort* pd1 = (ushort*)(ws + PW_D1);
  ushort* pd2 = (ushort*)(ws + PW_D2);
  ushort* pd3 = (ushort*)(ws + PW_D3);
  ushort* encw = (ushort*)(ws + W_ENCW);
  ushort* decw = (ushort*)(ws + W_DECW);
  ushort* h1b = (ushort*)(ws + W_H1B);
  ushort* h2b = (ushort*)(ws + W_H2B);
  ushort* h3b = (ushort*)(ws + W_H3B);
  ushort* h4b = (ushort*)(ws + W_H4B);
  ushort* deco = (ushort*)(ws + W_DECO);
  ushort* d1o = (ushort*)(ws + W_D1O);
  ushort* d2o = (ushort*)(ws + W_D2O);
  ushort* d3o = (ushort*)(ws + W_D3O);
  ushort* zb = (ushort*)(ws + W_ZB16);

  // ---- weight prepacks ----
  k_pack_convw<<<128, 256, 0, stream>>>(c2w, pc2, 64, 32, 32768);
  k_pack_convw<<<512, 256, 0, stream>>>(c3w, pc3, 128, 64, 131072);
  k_pack_convw<<<2048, 256, 0, stream>>>(c4w, pc4, 256, 128, 524288);
  k_pack_deconvw<<<512, 256, 0, stream>>>(d1w, pd1, 64, 128, 131072);
  k_pack_deconvw<<<128, 256, 0, stream>>>(d2w, pd2, 32, 64, 32768);
  k_pack_deconvw<<<32, 256, 0, stream>>>(d3w, pd3, 16, 32, 8192);
  k_pack_encw<<<2048, 256, 0, stream>>>(efw, encw);
  k_pack_decw<<<16384, 256, 0, stream>>>(dfw, decw);
  k_pack_decb<<<128, 256, 0, stream>>>(dfb, ws + W_DECB);

  // ---- SSM chain ----
  k_ssm_in<<<128, 256, 0, stream>>>(z_prev, act, siw, sib, ws + W_SSMIN);
  k_delta<<<128, 256, 0, stream>>>(ws + W_SSMIN, Dw, Db, ws + W_DELTA);
  k_bc<<<4, 256, 0, stream>>>(ws + W_SSMIN, Bw, Cw, ws + W_BT, ws + W_CT);
  k_state<<<128, 256, 0, stream>>>(ws + W_DELTA, ws + W_SSMIN, Alog, ws + W_BT,
                                   ws + W_CT, Dv, st_prev, out + O_STATE, ws + W_BELIEF);
  k_prior<<<128, 256, 0, stream>>>(ws + W_BELIEF, prw, prb, out);

  // ---- encoder ----
  k_timg<<<3072, 256, 0, stream>>>(img, ws + W_TIMG);
  k_conv1<<<4096, 256, 0, stream>>>(ws + W_TIMG, c1w, c1b, h1b);
  mfma_conv<32, 64, 4><<<1024, 256, 0, stream>>>(h1b, pc2, c2b, h2b, 128, 128, 64, 64);
  mfma_conv<64, 128, 2><<<1024, 256, 0, stream>>>(h2b, pc3, c3b, h3b, 64, 64, 32, 32);
  mfma_conv<128, 256, 2><<<512, 256, 0, stream>>>(h3b, pc4, c4b, h4b, 32, 32, 16, 16);

  // ---- enc_fc ----
  k_encfc_mfma<<<512, 256, 0, stream>>>(h4b, encw, ws + W_ENCP);
  k_encfc_red<<<128, 256, 0, stream>>>(ws + W_ENCP, efb, ws + W_CNN);

  // ---- posterior + reparam ----
  k_post<<<128, 256, 0, stream>>>(ws + W_CNN, ws + W_BELIEF, pow_, pob, out);
  k_z<<<64, 256, 0, stream>>>(eps, out, zb);

  // ---- decoder ----
  k_decfc_mfma<<<256, 256, 0, stream>>>(zb, decw, ws + W_DECB, deco);
  mfma_deconv<128, 64, 2><<<512, 256, 0, stream>>>(deco, pd1, d1b, d1o, 16, 16, 32, 32);
  mfma_deconv<64, 32, 2><<<1024, 256, 0, stream>>>(d1o, pd2, d2b, d2o, 32, 32, 64, 64);
  mfma_deconv<32, 16, 1><<<4096, 256, 0, stream>>>(d2o, pd3, d3b, d3o, 64, 64, 128, 128);
  k_d4<<<16384, 256, 0, stream>>>(d3o, d4w, d4b, ws + W_PREDT);

  // ---- predT -> out layout ----
  k_tout<<<1024, 256, 0, stream>>>(ws + W_PREDT, out + O_PRED);
}

// Round 5
// 713.709 us; speedup vs baseline: 46.0123x; 1.0928x over previous
//
#include <hip/hip_runtime.h>
#include <math.h>

#define BB 64
#define LATENT 256
#define ACTD 6
#define HIDD 512
#define DST 16

typedef __attribute__((ext_vector_type(8))) short bf16x8;
typedef __attribute__((ext_vector_type(4))) float f32x4;

static __device__ __forceinline__ ushort f2bf(float f) {
  unsigned u = __builtin_bit_cast(unsigned, f);
  unsigned r = (u + 0x7FFFu + ((u >> 16) & 1u)) >> 16;
  return (ushort)r;
}
static __device__ __forceinline__ float bf2f(ushort u) {
  return __builtin_bit_cast(float, ((unsigned)u) << 16);
}

// ---------------- output offsets (floats) ----------------
#define O_PRED   0
#define O_ZT     4194304
#define O_STATE  4210688
#define O_MUP    4734976
#define O_LVP    4751360
#define O_MUPO   4767744
#define O_LVPO   4784128

// ---------------- ws offsets (floats), lifetime-reused ----------------
#define W_SSMIN  0u
#define W_DELTA  32768u
#define W_BT     65536u
#define W_CT     66560u
#define W_BELIEF 67584u
#define W_CNN    100352u
#define W_ZB16   133120u      // 8192 u16
#define PW_C2    137216u      // 32768 u16
#define PW_C3    153600u      // 131072 u16
#define PW_C4    219136u      // 524288 u16
#define PW_D1    481280u      // 131072 u16
#define PW_D2    546816u      // 32768 u16
#define PW_D3    563200u      // 8192 u16
#define W_TIMG   602112u      // 12,582,912 f  [dead after conv1]
#define W_H1B    13185024u    // 33,554,432 u16 [dead after conv2]
#define W_H2B    29962240u    // 16,777,216 u16
#define W_H3B    38350848u    // 8,388,608 u16
#define W_H4B    42545152u    // 4,194,304 u16
// reuse (regions dead by write time):
#define W_ENCP   602112u      // 4,194,304 f   (TIMG)
#define W_DECO   8990720u     // 1,048,576 f   (TIMG)
#define W_D1O    10039296u    // 2,097,152 f   (TIMG)
#define W_D2O    13185024u    // 4,194,304 f   (H1B)
#define W_D3O    17379328u    // 8,388,608 f   (H1B)

#define ENC_KS 128

// fragment-order offset within a px-block: element (k, n) ->
//   (k>>5)*2048 + (n>>4)*NTS + ((k>>3)&3)*128 + (n&15)*8 + (k&7),  NTS=512 (256 if K=16)

// ================= SSM / small dense =================

__global__ void k_ssm_in(const float* __restrict__ z_prev, const float* __restrict__ act,
                         const float* __restrict__ w, const float* __restrict__ bias,
                         float* __restrict__ out) {
  int id = blockIdx.x * blockDim.x + threadIdx.x;
  int b = id >> 9, h = id & 511;
  const float* wr = w + (size_t)h * (LATENT + ACTD);
  const float* zr = z_prev + (size_t)b * LATENT;
  float acc = bias[h];
  #pragma unroll 4
  for (int k = 0; k < LATENT; ++k) acc += zr[k] * wr[k];
  const float* ar = act + (size_t)b * ACTD;
  #pragma unroll
  for (int k = 0; k < ACTD; ++k) acc += ar[k] * wr[LATENT + k];
  out[id] = acc / (1.f + expf(-acc));
}

__global__ void k_delta(const float* __restrict__ ssm_in, const float* __restrict__ w,
                        const float* __restrict__ bias, float* __restrict__ out) {
  int id = blockIdx.x * blockDim.x + threadIdx.x;
  int b = id >> 9, h = id & 511;
  const float* xr = ssm_in + (size_t)b * HIDD;
  const float* wr = w + (size_t)h * HIDD;
  float acc = bias[h];
  #pragma unroll 4
  for (int k = 0; k < HIDD; ++k) acc += xr[k] * wr[k];
  out[id] = fmaxf(acc, 0.f) + log1pf(expf(-fabsf(acc)));
}

__global__ void k_bc(const float* __restrict__ ssm_in, const float* __restrict__ Bw,
                     const float* __restrict__ Cw, float* __restrict__ Bt,
                     float* __restrict__ Ct) {
  int id = blockIdx.x * blockDim.x + threadIdx.x;
  if (id >= BB * DST) return;
  int b = id >> 4, n = id & 15;
  const float* xr = ssm_in + (size_t)b * HIDD;
  const float* br = Bw + (size_t)n * HIDD;
  const float* cr = Cw + (size_t)n * HIDD;
  float ab = 0.f, ac = 0.f;
  #pragma unroll 4
  for (int k = 0; k < HIDD; ++k) { ab += xr[k] * br[k]; ac += xr[k] * cr[k]; }
  Bt[id] = ab; Ct[id] = ac;
}

__global__ void k_state(const float* __restrict__ Delta, const float* __restrict__ ssm_in,
                        const float* __restrict__ A_log, const float* __restrict__ Bt,
                        const float* __restrict__ Ct, const float* __restrict__ Dv,
                        const float* __restrict__ prev, float* __restrict__ state_out,
                        float* __restrict__ belief) {
  int id = blockIdx.x * blockDim.x + threadIdx.x;
  int b = id >> 9, h = id & 511;
  float d = Delta[id], si = ssm_in[id];
  float bel = Dv[h] * si;
  const float* al = A_log + (size_t)h * DST;
  const float* bt = Bt + (size_t)b * DST;
  const float* ct = Ct + (size_t)b * DST;
  const float* sp = prev + (size_t)id * DST;
  float* so = state_out + (size_t)id * DST;
  #pragma unroll
  for (int n = 0; n < DST; ++n) {
    float A = -expf(al[n]);
    float st = expf(d * A) * sp[n] + d * bt[n] * si;
    so[n] = st;
    bel += st * ct[n];
  }
  belief[id] = bel;
}

__global__ void k_prior(const float* __restrict__ belief, const float* __restrict__ w,
                        const float* __restrict__ bias, float* __restrict__ out) {
  int id = blockIdx.x * blockDim.x + threadIdx.x;
  int b = id >> 9, j = id & 511;
  const float* xr = belief + (size_t)b * HIDD;
  const float* wr = w + (size_t)j * HIDD;
  float acc = bias[j];
  #pragma unroll 4
  for (int k = 0; k < HIDD; ++k) acc += xr[k] * wr[k];
  if (j < 256) out[O_MUP + b * 256 + j] = acc;
  else         out[O_LVP + b * 256 + (j - 256)] = acc;
}

// ================= weight prepacks (fragment order) =================
// conv w [Cout][Cin][4][4] -> [Cout/16][16Cin/32][kg4][m16][k8], k = tap*Cin+ci
__global__ void k_pack_convw(const float* __restrict__ w, ushort* __restrict__ o,
                             int Cout, int Cin, int n) {
  int id = blockIdx.x * blockDim.x + threadIdx.x;
  if (id >= n) return;
  int NCH = Cin / 2;
  int per = NCH * 512;
  int mt = id / per, r = id % per;
  int kcg = r >> 9, s = r & 511;
  int kg = s >> 7, m = (s >> 3) & 15, k8 = s & 7;
  int co = mt * 16 + m;
  int k = kcg * 32 + kg * 8 + k8;
  int tap = k / Cin, ci = k % Cin;
  o[id] = f2bf(w[(size_t)(co * Cin + ci) * 16 + tap]);
}

// deconv w [Cin][Cout][4][4] -> [cls][Cout/16][4Cin/32][512], k = t*Cin+ci
__global__ void k_pack_deconvw(const float* __restrict__ w, ushort* __restrict__ o,
                               int Cout, int Cin, int n) {
  int id = blockIdx.x * blockDim.x + threadIdx.x;
  if (id >= n) return;
  int NCH = Cin / 8;
  int perM = NCH * 512;
  int perC = (Cout / 16) * perM;
  int cls = id / perC, r = id % perC;
  int mt = r / perM, r2 = r % perM;
  int kcg = r2 >> 9, s = r2 & 511;
  int kg = s >> 7, m = (s >> 3) & 15, k8 = s & 7;
  int co = mt * 16 + m;
  int k = kcg * 32 + kg * 8 + k8;
  int t = k / Cin, ci = k % Cin;
  int p = (cls >> 1) + 2 * (t >> 1);
  int q = (cls & 1) + 2 * (t & 1);
  o[id] = f2bf(w[(size_t)(ci * Cout + co) * 16 + p * 4 + q]);
}

// ================= img transpose =================
// img [B,3,256,256] -> timg [3, 65536, B] f32
__global__ __launch_bounds__(256) void k_timg(const float* __restrict__ img,
                                              float* __restrict__ timg) {
  int blk = blockIdx.x;
  int c = blk >> 10, p0 = (blk & 1023) << 6;
  __shared__ float t[64 * 65];
  int tid = threadIdx.x;
  #pragma unroll
  for (int i = 0; i < 16; ++i) {
    int idx = tid + i * 256;
    int b = idx >> 6, pr = idx & 63;
    t[pr * 65 + b] = img[((size_t)b * 3 + c) * 65536 + p0 + pr];
  }
  __syncthreads();
  #pragma unroll
  for (int i = 0; i < 16; ++i) {
    int idx = tid + i * 256;
    int pr = idx >> 6, b = idx & 63;
    timg[((size_t)c * 65536 + p0 + pr) * 64 + b] = t[pr * 65 + b];
  }
}

// ================= conv1: f32 direct (Cin=3), frag-order bf16 out =================
// in timg [3][65536][64] f32; out h1b frag-order px-blocks of 32ch x 64b
__global__ __launch_bounds__(256) void k_conv1(const float* __restrict__ in,
                                               const float* __restrict__ w,
                                               const float* __restrict__ bias,
                                               ushort* __restrict__ out) {
  int wid = __builtin_amdgcn_readfirstlane(blockIdx.x * 4 + (threadIdx.x >> 6));
  int lane = threadIdx.x & 63;
  int x4 = wid & 31; int t = wid >> 5;
  int oy = t & 127; int cg = t >> 7;      // cg 0..3
  int co0 = cg * 8;
  int ox0 = x4 << 2;
  int ixb = ox0 * 2 - 1;
  float acc[8][4];
  #pragma unroll
  for (int u = 0; u < 8; ++u) {
    float bv = bias[co0 + u];
    #pragma unroll
    for (int j = 0; j < 4; ++j) acc[u][j] = bv;
  }
  for (int ci = 0; ci < 3; ++ci) {
    const float* ip = in + ((size_t)ci * 65536) * 64 + lane;
    const float* wp = w + (size_t)co0 * 48 + ci * 16;
    #pragma unroll
    for (int ky = 0; ky < 4; ++ky) {
      int iy = oy * 2 - 1 + ky;
      if ((unsigned)iy >= 256u) continue;
      const float* rp = ip + (size_t)iy * 256 * 64;
      float x[10];
      #pragma unroll
      for (int j = 0; j < 10; ++j) {
        int ix = ixb + j;
        x[j] = ((unsigned)ix < 256u) ? rp[(size_t)ix * 64] : 0.f;
      }
      #pragma unroll
      for (int u = 0; u < 8; ++u) {
        const float* wq = wp + (size_t)u * 48 + ky * 4;
        float w0 = wq[0], w1 = wq[1], w2 = wq[2], w3 = wq[3];
        acc[u][0] += x[0]*w0 + x[1]*w1 + x[2]*w2 + x[3]*w3;
        acc[u][1] += x[2]*w0 + x[3]*w1 + x[4]*w2 + x[5]*w3;
        acc[u][2] += x[4]*w0 + x[5]*w1 + x[6]*w2 + x[7]*w3;
        acc[u][3] += x[6]*w0 + x[7]*w1 + x[8]*w2 + x[9]*w3;
      }
    }
  }
  // frag-order write: px-block 2048 elems; (k=co, n=b): (b>>4)*512 + cg*128 + (b&15)*8 + u
  #pragma unroll
  for (int j = 0; j < 4; ++j) {
    int px = oy * 128 + ox0 + j;
    size_t off = (size_t)px * 2048 + (size_t)(lane >> 4) * 512 + cg * 128 + (lane & 15) * 8;
    ushort tmp[8];
    #pragma unroll
    for (int u = 0; u < 8; ++u) tmp[u] = f2bf(fmaxf(acc[u][j], 0.f));
    uint4 pk;
    pk.x = tmp[0] | ((unsigned)tmp[1] << 16);
    pk.y = tmp[2] | ((unsigned)tmp[3] << 16);
    pk.z = tmp[4] | ((unsigned)tmp[5] << 16);
    pk.w = tmp[6] | ((unsigned)tmp[7] << 16);
    *(uint4*)(out + off) = pk;
  }
}

// ================= MFMA conv 4x4 s2 p1 + relu (frag-order in/out) =================
template<int CIN, int COUT, int MT>
__global__ __launch_bounds__(256) void mfma_conv(const ushort* __restrict__ in,
                                                 const ushort* __restrict__ wp,
                                                 const float* __restrict__ bias,
                                                 ushort* __restrict__ out,
                                                 int Hin, int Win, int Hout, int Wout) {
  constexpr int NMG = COUT / (16 * MT);
  constexpr int NKC = CIN / 32;
  constexpr int NCH = 16 * NKC;
  int wid = __builtin_amdgcn_readfirstlane(blockIdx.x * 4 + (threadIdx.x >> 6));
  int lane = threadIdx.x & 63;
  int mg = wid % NMG;
  int px = wid / NMG;
  int ox = px % Wout, oy = px / Wout;
  if (oy >= Hout) return;
  int mtile0 = mg * MT;
  f32x4 zero = {0.f, 0.f, 0.f, 0.f};
  f32x4 acc[MT][4];
  #pragma unroll
  for (int mt = 0; mt < MT; ++mt)
    #pragma unroll
    for (int nt = 0; nt < 4; ++nt) acc[mt][nt] = zero;
  const ushort* wbase = wp + (size_t)mtile0 * NCH * 512 + lane * 8;
  const size_t mstride = (size_t)NCH * 512;

  for (int ky = 0; ky < 4; ++ky) {
    int iy = 2 * oy - 1 + ky;
    if ((unsigned)iy >= (unsigned)Hin) continue;
    for (int kx = 0; kx < 4; ++kx) {
      int ix = 2 * ox - 1 + kx;
      if ((unsigned)ix >= (unsigned)Win) continue;
      const ushort* ib = in + (size_t)(iy * Win + ix) * (CIN * 64) + lane * 8;
      int tap = ky * 4 + kx;
      #pragma unroll
      for (int kc = 0; kc < NKC; ++kc) {
        int kcg = tap * NKC + kc;
        bf16x8 a[MT], bb[4];
        #pragma unroll
        for (int mt = 0; mt < MT; ++mt)
          a[mt] = *(const bf16x8*)(wbase + mt * mstride + (size_t)kcg * 512);
        #pragma unroll
        for (int nt = 0; nt < 4; ++nt)
          bb[nt] = *(const bf16x8*)(ib + kc * 2048 + nt * 512);
        #pragma unroll
        for (int mt = 0; mt < MT; ++mt)
          #pragma unroll
          for (int nt = 0; nt < 4; ++nt)
            acc[mt][nt] = __builtin_amdgcn_mfma_f32_16x16x32_bf16(a[mt], bb[nt], acc[mt][nt], 0, 0, 0);
      }
    }
  }
  int ml = lane & 15, rb = (lane >> 4) * 4;
  #pragma unroll
  for (int mt = 0; mt < MT; ++mt) {
    int co = mtile0 * 16 + mt * 16 + rb;
    f32x4 bv = *(const f32x4*)(bias + co);
    #pragma unroll
    for (int nt = 0; nt < 4; ++nt) {
      int b = nt * 16 + ml;
      float v0 = fmaxf(acc[mt][nt][0] + bv[0], 0.f);
      float v1 = fmaxf(acc[mt][nt][1] + bv[1], 0.f);
      float v2 = fmaxf(acc[mt][nt][2] + bv[2], 0.f);
      float v3 = fmaxf(acc[mt][nt][3] + bv[3], 0.f);
      uint2 pk;
      pk.x = (unsigned)f2bf(v0) | ((unsigned)f2bf(v1) << 16);
      pk.y = (unsigned)f2bf(v2) | ((unsigned)f2bf(v3) << 16);
      size_t off = (size_t)px * (COUT * 64) + (size_t)(co >> 5) * 2048 + nt * 512
                 + ((co >> 3) & 3) * 128 + ml * 8 + (co & 7);
      *(uint2*)(out + off) = pk;
    }
  }
}

// ================= MFMA transposed conv 4x4 s2 p1 + relu (frag-order) =================
template<int CIN, int COUT, int MT, bool RELU>
__global__ __launch_bounds__(256) void mfma_deconv(const ushort* __restrict__ in,
                                                   const ushort* __restrict__ wp,
                                                   const float* __restrict__ bias,
                                                   ushort* __restrict__ out,
                                                   int Hin, int Win, int Hout, int Wout) {
  constexpr int NMG = COUT / (16 * MT);
  constexpr int NKC = CIN / 32;
  constexpr int NCH = 4 * NKC;
  constexpr int NTS = (COUT >= 32) ? 512 : (COUT * 16);
  int wid = __builtin_amdgcn_readfirstlane(blockIdx.x * 4 + (threadIdx.x >> 6));
  int lane = threadIdx.x & 63;
  int mg = wid % NMG; int r1 = wid / NMG;
  int wo2 = Wout >> 1;
  int pc = (Hout >> 1) * wo2;
  int pxc = r1 % pc; int cls = r1 / pc;
  if (cls >= 4) return;
  int p0 = cls >> 1, q0 = cls & 1;
  int tx = pxc % wo2, ty = pxc / wo2;
  int oy = 2 * ty + 1 - p0, ox = 2 * tx + 1 - q0;
  int iy0 = (oy + 1 - p0) >> 1, ix0 = (ox + 1 - q0) >> 1;
  int mtile0 = mg * MT;
  f32x4 zero = {0.f, 0.f, 0.f, 0.f};
  f32x4 acc[MT][4];
  #pragma unroll
  for (int mt = 0; mt < MT; ++mt)
    #pragma unroll
    for (int nt = 0; nt < 4; ++nt) acc[mt][nt] = zero;
  const ushort* wbase = wp + ((size_t)cls * (COUT / 16) + mtile0) * NCH * 512 + lane * 8;
  const size_t mstride = (size_t)NCH * 512;

  for (int i = 0; i < 2; ++i) {
    int iy = iy0 - i;
    if ((unsigned)iy >= (unsigned)Hin) continue;
    for (int j = 0; j < 2; ++j) {
      int ix = ix0 - j;
      if ((unsigned)ix >= (unsigned)Win) continue;
      const ushort* ib = in + (size_t)(iy * Win + ix) * (CIN * 64) + lane * 8;
      int tap = i * 2 + j;
      #pragma unroll
      for (int kc = 0; kc < NKC; ++kc) {
        int kcg = tap * NKC + kc;
        bf16x8 a[MT], bb[4];
        #pragma unroll
        for (int mt = 0; mt < MT; ++mt)
          a[mt] = *(const bf16x8*)(wbase + mt * mstride + (size_t)kcg * 512);
        #pragma unroll
        for (int nt = 0; nt < 4; ++nt)
          bb[nt] = *(const bf16x8*)(ib + kc * 2048 + nt * 512);
        #pragma unroll
        for (int mt = 0; mt < MT; ++mt)
          #pragma unroll
          for (int nt = 0; nt < 4; ++nt)
            acc[mt][nt] = __builtin_amdgcn_mfma_f32_16x16x32_bf16(a[mt], bb[nt], acc[mt][nt], 0, 0, 0);
      }
    }
  }
  int ml = lane & 15, rb = (lane >> 4) * 4;
  int px = oy * Wout + ox;
  #pragma unroll
  for (int mt = 0; mt < MT; ++mt) {
    int co = mtile0 * 16 + mt * 16 + rb;
    f32x4 bv = *(const f32x4*)(bias + co);
    #pragma unroll
    for (int nt = 0; nt < 4; ++nt) {
      int b = nt * 16 + ml;
      float v0 = acc[mt][nt][0] + bv[0];
      float v1 = acc[mt][nt][1] + bv[1];
      float v2 = acc[mt][nt][2] + bv[2];
      float v3 = acc[mt][nt][3] + bv[3];
      if (RELU) { v0=fmaxf(v0,0.f); v1=fmaxf(v1,0.f); v2=fmaxf(v2,0.f); v3=fmaxf(v3,0.f); }
      uint2 pk;
      pk.x = (unsigned)f2bf(v0) | ((unsigned)f2bf(v1) << 16);
      pk.y = (unsigned)f2bf(v2) | ((unsigned)f2bf(v3) << 16);
      size_t off = (size_t)px * (COUT * 64) + (size_t)(co >> 5) * 2048 + (size_t)nt * NTS
                 + ((co >> 3) & 3) * 128 + ml * 8 + (co & 7);
      *(uint2*)(out + off) = pk;
    }
  }
}

// ================= enc_fc MFMA: direct f32 weights, frag-order h4 =================
// h4 frag-order [256px][8cc][2048]; wE f32 [512][ci*256+px]
__global__ __launch_bounds__(256) void k_encfc_mfma(const ushort* __restrict__ h4,
                                                    const float* __restrict__ wE,
                                                    float* __restrict__ partial) {
  int wid = __builtin_amdgcn_readfirstlane(blockIdx.x * 4 + (threadIdx.x >> 6)); // 0..2047
  int lane = threadIdx.x & 63;
  int mg = wid & 15, ks = wid >> 4;     // ks 0..127
  int ccf = ks & 7, pxg = ks >> 3;      // ci-chunk 0..7, px-group 0..15
  int co0 = mg * 32;
  int ml = lane & 15, kl = (lane >> 4) * 8;
  int cb = ccf * 32;
  f32x4 zero = {0.f, 0.f, 0.f, 0.f};
  f32x4 acc[2][4];
  #pragma unroll
  for (int mt = 0; mt < 2; ++mt)
    #pragma unroll
    for (int nt = 0; nt < 4; ++nt) acc[mt][nt] = zero;
  const float* wr0 = wE + (size_t)(co0 + ml) * 65536 + (size_t)(cb + kl) * 256;
  #pragma unroll 2
  for (int j = 0; j < 16; ++j) {
    int px = pxg * 16 + j;
    bf16x8 a[2];
    #pragma unroll
    for (int mt = 0; mt < 2; ++mt) {
      const float* wr = wr0 + (size_t)mt * 16 * 65536 + px;
      bf16x8 av;
      #pragma unroll
      for (int q = 0; q < 8; ++q) av[q] = (short)f2bf(wr[(size_t)q * 256]);
      a[mt] = av;
    }
    const ushort* hb = h4 + (size_t)px * 16384 + ccf * 2048 + lane * 8;
    bf16x8 bb[4];
    #pragma unroll
    for (int nt = 0; nt < 4; ++nt)
      bb[nt] = *(const bf16x8*)(hb + nt * 512);
    #pragma unroll
    for (int mt = 0; mt < 2; ++mt)
      #pragma unroll
      for (int nt = 0; nt < 4; ++nt)
        acc[mt][nt] = __builtin_amdgcn_mfma_f32_16x16x32_bf16(a[mt], bb[nt], acc[mt][nt], 0, 0, 0);
  }
  int rb = (lane >> 4) * 4;
  #pragma unroll
  for (int mt = 0; mt < 2; ++mt) {
    int co = co0 + mt * 16 + rb;
    #pragma unroll
    for (int nt = 0; nt < 4; ++nt) {
      int b = nt * 16 + ml;
      #pragma unroll
      for (int r = 0; r < 4; ++r)
        partial[((size_t)(co + r) * ENC_KS + ks) * 64 + b] = acc[mt][nt][r];
    }
  }
}

__global__ void k_encfc_red(const float* __restrict__ partial, const float* __restrict__ bias,
                            float* __restrict__ cnn) {
  int id = blockIdx.x * blockDim.x + threadIdx.x;  // o*64 + b
  int o = id >> 6, b = id & 63;
  float acc = bias[o];
  #pragma unroll 8
  for (int s = 0; s < ENC_KS; ++s) acc += partial[((size_t)o * ENC_KS + s) * 64 + b];
  cnn[(size_t)b * 512 + o] = fmaxf(acc, 0.f);
}

// ================= posterior / reparam =================

__global__ void k_post(const float* __restrict__ cnn, const float* __restrict__ belief,
                       const float* __restrict__ w, const float* __restrict__ bias,
                       float* __restrict__ out) {
  int id = blockIdx.x * blockDim.x + threadIdx.x;
  int b = id >> 9, j = id & 511;
  const float* wr = w + (size_t)j * 1024;
  const float* cr = cnn + (size_t)b * HIDD;
  const float* br = belief + (size_t)b * HIDD;
  float acc = bias[j];
  #pragma unroll 4
  for (int k = 0; k < HIDD; ++k) acc += cr[k] * wr[k];
  #pragma unroll 4
  for (int k = 0; k < HIDD; ++k) acc += br[k] * wr[512 + k];
  if (j < 256) out[O_MUPO + b * 256 + j] = acc;
  else         out[O_LVPO + b * 256 + (j - 256)] = acc;
}

__global__ void k_z(const float* __restrict__ eps, float* __restrict__ out,
                    ushort* __restrict__ zb) {
  int id = blockIdx.x * blockDim.x + threadIdx.x;
  int b = id >> 8, i = id & 255;
  float mu = out[O_MUPO + b * 256 + i];
  float lv = out[O_LVPO + b * 256 + i];
  float z = mu + eps[id] * expf(0.5f * lv);
  out[O_ZT + b * 256 + i] = z;
  if (i < 128) zb[b * 128 + i] = f2bf(z);
}

// ================= dec_fc MFMA: direct f32 weights, frag-order out =================
// zb bf16 [64][128]; dfw f32 [co*256+pix][128]; dfb f32; deco frag-order [pix][128co x 64b]
__global__ __launch_bounds__(256) void k_decfc_mfma(const ushort* __restrict__ zb,
                                                    const float* __restrict__ dfw,
                                                    const float* __restrict__ dfb,
                                                    ushort* __restrict__ dec) {
  int wid = __builtin_amdgcn_readfirstlane(blockIdx.x * 4 + (threadIdx.x >> 6)); // 0..1023
  int lane = threadIdx.x & 63;
  int m0 = wid * 32;
  int ml = lane & 15, kl = (lane >> 4) * 8;
  f32x4 zero = {0.f, 0.f, 0.f, 0.f};
  f32x4 acc[2][4];
  #pragma unroll
  for (int mt = 0; mt < 2; ++mt)
    #pragma unroll
    for (int nt = 0; nt < 4; ++nt) acc[mt][nt] = zero;
  #pragma unroll
  for (int kc = 0; kc < 4; ++kc) {
    bf16x8 a[2], bb[4];
    #pragma unroll
    for (int mt = 0; mt < 2; ++mt) {
      int m_r = m0 + mt * 16 + ml;
      const float* wr = dfw + (size_t)((m_r & 127) * 256 + (m_r >> 7)) * 128 + kc * 32 + kl;
      float4 u0 = *(const float4*)wr;
      float4 u1 = *(const float4*)(wr + 4);
      bf16x8 av;
      av[0] = (short)f2bf(u0.x); av[1] = (short)f2bf(u0.y);
      av[2] = (short)f2bf(u0.z); av[3] = (short)f2bf(u0.w);
      av[4] = (short)f2bf(u1.x); av[5] = (short)f2bf(u1.y);
      av[6] = (short)f2bf(u1.z); av[7] = (short)f2bf(u1.w);
      a[mt] = av;
    }
    #pragma unroll
    for (int nt = 0; nt < 4; ++nt)
      bb[nt] = *(const bf16x8*)(zb + (size_t)(nt * 16 + ml) * 128 + kc * 32 + kl);
    #pragma unroll
    for (int mt = 0; mt < 2; ++mt)
      #pragma unroll
      for (int nt = 0; nt < 4; ++nt)
        acc[mt][nt] = __builtin_amdgcn_mfma_f32_16x16x32_bf16(a[mt], bb[nt], acc[mt][nt], 0, 0, 0);
  }
  int rb = (lane >> 4) * 4;
  #pragma unroll
  for (int mt = 0; mt < 2; ++mt) {
    int m = m0 + mt * 16 + rb;
    int pix = m >> 7, co = m & 127;
    float bv0 = dfb[(size_t)(co + 0) * 256 + pix];
    float bv1 = dfb[(size_t)(co + 1) * 256 + pix];
    float bv2 = dfb[(size_t)(co + 2) * 256 + pix];
    float bv3 = dfb[(size_t)(co + 3) * 256 + pix];
    #pragma unroll
    for (int nt = 0; nt < 4; ++nt) {
      uint2 pk;
      pk.x = (unsigned)f2bf(acc[mt][nt][0] + bv0) | ((unsigned)f2bf(acc[mt][nt][1] + bv1) << 16);
      pk.y = (unsigned)f2bf(acc[mt][nt][2] + bv2) | ((unsigned)f2bf(acc[mt][nt][3] + bv3) << 16);
      size_t off = (size_t)pix * 8192 + (size_t)(co >> 5) * 2048 + nt * 512
                 + ((co >> 3) & 3) * 128 + ml * 8 + (co & 7);
      *(uint2*)(dec + off) = pk;
    }
  }
}

// ================= d4 fused with output transpose =================
// in frag-order [128][128] px-blocks of 16ch x 64b (NTS=256); out [B][65536]
__global__ __launch_bounds__(256) void k_d4t(const ushort* __restrict__ in,
                                             const float* __restrict__ w,
                                             const float* __restrict__ bias,
                                             float* __restrict__ out) {
  __shared__ float lds[64][65];
  int blk = blockIdx.x;
  int oy = blk >> 2, ox0 = (blk & 3) << 6;
  int t = threadIdx.x;
  int b = t & 63, sub = t >> 6;
  float bv = bias[0];
  for (int j = 0; j < 16; ++j) {
    int oxl = j * 4 + sub;
    int ox = ox0 + oxl;
    int p0 = (oy + 1) & 1, q0 = (ox + 1) & 1;
    int iy0 = (oy + 1 - p0) >> 1, ix0 = (ox + 1 - q0) >> 1;
    float acc = bv;
    #pragma unroll
    for (int i = 0; i < 2; ++i) {
      int iy = iy0 - i;
      if ((unsigned)iy >= 128u) continue;
      int p = p0 + 2 * i;
      #pragma unroll
      for (int jj = 0; jj < 2; ++jj) {
        int ix = ix0 - jj;
        if ((unsigned)ix >= 128u) continue;
        int q = q0 + 2 * jj;
        const ushort* base = in + (size_t)(iy * 128 + ix) * 1024 + (b >> 4) * 256 + (b & 15) * 8;
        bf16x8 v0 = *(const bf16x8*)(base);
        bf16x8 v1 = *(const bf16x8*)(base + 128);
        const float* wq = w + p * 4 + q;
        #pragma unroll
        for (int ci = 0; ci < 8; ++ci) acc += bf2f((ushort)v0[ci]) * wq[ci * 16];
        #pragma unroll
        for (int ci = 0; ci < 8; ++ci) acc += bf2f((ushort)v1[ci]) * wq[(ci + 8) * 16];
      }
    }
    lds[oxl][b] = acc;
  }
  __syncthreads();
  #pragma unroll
  for (int j = 0; j < 16; ++j) {
    int idx = t + j * 256;
    int b2 = idx >> 6, oxl = idx & 63;
    out[(size_t)b2 * 65536 + oy * 256 + ox0 + oxl] = lds[oxl][b2];
  }
}

// ================= launch =================

extern "C" void kernel_launch(void* const* d_in, const int* in_sizes, int n_in,
                              void* d_out, int out_size, void* d_ws, size_t ws_size,
                              hipStream_t stream) {
  const float* img      = (const float*)d_in[0];
  const float* act      = (const float*)d_in[1];
  const float* z_prev   = (const float*)d_in[2];
  const float* st_prev  = (const float*)d_in[3];
  const float* eps      = (const float*)d_in[4];
  const float* c1w = (const float*)d_in[5];  const float* c1b = (const float*)d_in[6];
  const float* c2w = (const float*)d_in[7];  const float* c2b = (const float*)d_in[8];
  const float* c3w = (const float*)d_in[9];  const float* c3b = (const float*)d_in[10];
  const float* c4w = (const float*)d_in[11]; const float* c4b = (const float*)d_in[12];
  const float* efw = (const float*)d_in[13]; const float* efb = (const float*)d_in[14];
  const float* pow_ = (const float*)d_in[15]; const float* pob = (const float*)d_in[16];
  const float* prw = (const float*)d_in[17]; const float* prb = (const float*)d_in[18];
  const float* siw = (const float*)d_in[19]; const float* sib = (const float*)d_in[20];
  const float* Alog = (const float*)d_in[21];
  const float* Bw = (const float*)d_in[22];  const float* Cw = (const float*)d_in[23];
  const float* Dw = (const float*)d_in[24];  const float* Db = (const float*)d_in[25];
  const float* Dv = (const float*)d_in[26];
  const float* dfw = (const float*)d_in[27]; const float* dfb = (const float*)d_in[28];
  const float* d1w = (const float*)d_in[29]; const float* d1b = (const float*)d_in[30];
  const float* d2w = (const float*)d_in[31]; const float* d2b = (const float*)d_in[32];
  const float* d3w = (const float*)d_in[33]; const float* d3b = (const float*)d_in[34];
  const float* d4w = (const float*)d_in[35]; const float* d4b = (const float*)d_in[36];

  float* ws = (float*)d_ws;
  float* out = (float*)d_out;

  ushort* pc2 = (ushort*)(ws + PW_C2);
  ushort* pc3 = (ushort*)(ws + PW_C3);
  ushort* pc4 = (ushort*)(ws + PW_C4);
  ushort* pd1 = (ushort*)(ws + PW_D1);
  ushort* pd2 = (ushort*)(ws + PW_D2);
  ushort* pd3 = (ushort*)(ws + PW_D3);
  ushort* h1b = (ushort*)(ws + W_H1B);
  ushort* h2b = (ushort*)(ws + W_H2B);
  ushort* h3b = (ushort*)(ws + W_H3B);
  ushort* h4b = (ushort*)(ws + W_H4B);
  ushort* deco = (ushort*)(ws + W_DECO);
  ushort* d1o = (ushort*)(ws + W_D1O);
  ushort* d2o = (ushort*)(ws + W_D2O);
  ushort* d3o = (ushort*)(ws + W_D3O);
  ushort* zb = (ushort*)(ws + W_ZB16);

  // ---- weight prepacks (frag order) ----
  k_pack_convw<<<128, 256, 0, stream>>>(c2w, pc2, 64, 32, 32768);
  k_pack_convw<<<512, 256, 0, stream>>>(c3w, pc3, 128, 64, 131072);
  k_pack_convw<<<2048, 256, 0, stream>>>(c4w, pc4, 256, 128, 524288);
  k_pack_deconvw<<<512, 256, 0, stream>>>(d1w, pd1, 64, 128, 131072);
  k_pack_deconvw<<<128, 256, 0, stream>>>(d2w, pd2, 32, 64, 32768);
  k_pack_deconvw<<<32, 256, 0, stream>>>(d3w, pd3, 16, 32, 8192);

  // ---- SSM chain ----
  k_ssm_in<<<128, 256, 0, stream>>>(z_prev, act, siw, sib, ws + W_SSMIN);
  k_delta<<<128, 256, 0, stream>>>(ws + W_SSMIN, Dw, Db, ws + W_DELTA);
  k_bc<<<4, 256, 0, stream>>>(ws + W_SSMIN, Bw, Cw, ws + W_BT, ws + W_CT);
  k_state<<<128, 256, 0, stream>>>(ws + W_DELTA, ws + W_SSMIN, Alog, ws + W_BT,
                                   ws + W_CT, Dv, st_prev, out + O_STATE, ws + W_BELIEF);
  k_prior<<<128, 256, 0, stream>>>(ws + W_BELIEF, prw, prb, out);

  // ---- encoder ----
  k_timg<<<3072, 256, 0, stream>>>(img, ws + W_TIMG);
  k_conv1<<<4096, 256, 0, stream>>>(ws + W_TIMG, c1w, c1b, h1b);
  mfma_conv<32, 64, 2><<<2048, 256, 0, stream>>>(h1b, pc2, c2b, h2b, 128, 128, 64, 64);
  mfma_conv<64, 128, 2><<<1024, 256, 0, stream>>>(h2b, pc3, c3b, h3b, 64, 64, 32, 32);
  mfma_conv<128, 256, 1><<<1024, 256, 0, stream>>>(h3b, pc4, c4b, h4b, 32, 32, 16, 16);

  // ---- enc_fc ----
  k_encfc_mfma<<<512, 256, 0, stream>>>(h4b, efw, ws + W_ENCP);
  k_encfc_red<<<128, 256, 0, stream>>>(ws + W_ENCP, efb, ws + W_CNN);

  // ---- posterior + reparam ----
  k_post<<<128, 256, 0, stream>>>(ws + W_CNN, ws + W_BELIEF, pow_, pob, out);
  k_z<<<64, 256, 0, stream>>>(eps, out, zb);

  // ---- decoder ----
  k_decfc_mfma<<<256, 256, 0, stream>>>(zb, dfw, dfb, deco);
  mfma_deconv<128, 64, 1, true><<<1024, 256, 0, stream>>>(deco, pd1, d1b, d1o, 16, 16, 32, 32);
  mfma_deconv<64, 32, 1, true><<<2048, 256, 0, stream>>>(d1o, pd2, d2b, d2o, 32, 32, 64, 64);
  mfma_deconv<32, 16, 1, true><<<4096, 256, 0, stream>>>(d2o, pd3, d3b, d3o, 64, 64, 128, 128);
  k_d4t<<<1024, 256, 0, stream>>>(d3o, d4w, d4b, out + O_PRED);
}

// Round 6
// 554.991 us; speedup vs baseline: 59.1711x; 1.2860x over previous
//
#include <hip/hip_runtime.h>
#include <math.h>

#define BB 64
#define LATENT 256
#define ACTD 6
#define HIDD 512
#define DST 16

typedef __attribute__((ext_vector_type(8))) short bf16x8;
typedef __attribute__((ext_vector_type(4))) float f32x4;

static __device__ __forceinline__ ushort f2bf(float f) {
  unsigned u = __builtin_bit_cast(unsigned, f);
  unsigned r = (u + 0x7FFFu + ((u >> 16) & 1u)) >> 16;
  return (ushort)r;
}
static __device__ __forceinline__ float bf2f(ushort u) {
  return __builtin_bit_cast(float, ((unsigned)u) << 16);
}

// ---------------- output offsets (floats) ----------------
#define O_PRED   0
#define O_ZT     4194304
#define O_STATE  4210688
#define O_MUP    4734976
#define O_LVP    4751360
#define O_MUPO   4767744
#define O_LVPO   4784128

// ---------------- ws offsets (floats), lifetime-reused ----------------
#define W_SSMIN  0u
#define W_DELTA  32768u
#define W_BT     65536u
#define W_CT     66560u
#define W_BELIEF 67584u
#define W_CNN    100352u
#define W_ZB16   133120u      // 8192 u16
#define PW_C2    137216u      // 32768 u16
#define PW_C3    153600u      // 131072 u16
#define PW_C4    219136u      // 524288 u16
#define PW_D1    481280u      // 131072 u16
#define PW_D2    546816u      // 32768 u16
#define PW_D3    563200u      // 8192 u16
#define W_TIMG   602112u      // timg bf16 (6.29M f32 equiv), region reserved to 13185024
#define W_H1B    13185024u    // 33,554,432 u16 [dead after conv2]
#define W_H2B    29962240u    // 16,777,216 u16
#define W_H3B    38350848u    // 8,388,608 u16
#define W_H4B    42545152u    // 4,194,304 u16
// reuse (regions dead by write time):
#define W_ENCP   602112u      // 4,194,304 f   (TIMG region, dead after conv1)
#define W_DECO   8990720u     // 1,048,576 f   (TIMG region)
#define W_D1O    10039296u    // 2,097,152 f   (TIMG region)
#define W_D2O    13185024u    // 4,194,304 f   (H1B)
#define W_D3O    17379328u    // 8,388,608 f   (H1B)

#define ENC_KS 128

// fragment-order offset within a px-block: element (k, n) ->
//   (k>>5)*2048 + (n>>4)*NTS + ((k>>3)&3)*128 + (n&15)*8 + (k&7),  NTS=512 (256 if K=16)

// ================= SSM / small dense =================

__global__ void k_ssm_in(const float* __restrict__ z_prev, const float* __restrict__ act,
                         const float* __restrict__ w, const float* __restrict__ bias,
                         float* __restrict__ out) {
  int id = blockIdx.x * blockDim.x + threadIdx.x;
  int b = id >> 9, h = id & 511;
  const float* wr = w + (size_t)h * (LATENT + ACTD);
  const float* zr = z_prev + (size_t)b * LATENT;
  float acc = bias[h];
  #pragma unroll 4
  for (int k = 0; k < LATENT; ++k) acc += zr[k] * wr[k];
  const float* ar = act + (size_t)b * ACTD;
  #pragma unroll
  for (int k = 0; k < ACTD; ++k) acc += ar[k] * wr[LATENT + k];
  out[id] = acc / (1.f + expf(-acc));
}

__global__ void k_delta(const float* __restrict__ ssm_in, const float* __restrict__ w,
                        const float* __restrict__ bias, float* __restrict__ out) {
  int id = blockIdx.x * blockDim.x + threadIdx.x;
  int b = id >> 9, h = id & 511;
  const float* xr = ssm_in + (size_t)b * HIDD;
  const float* wr = w + (size_t)h * HIDD;
  float acc = bias[h];
  #pragma unroll 4
  for (int k = 0; k < HIDD; ++k) acc += xr[k] * wr[k];
  out[id] = fmaxf(acc, 0.f) + log1pf(expf(-fabsf(acc)));
}

__global__ void k_bc(const float* __restrict__ ssm_in, const float* __restrict__ Bw,
                     const float* __restrict__ Cw, float* __restrict__ Bt,
                     float* __restrict__ Ct) {
  int id = blockIdx.x * blockDim.x + threadIdx.x;
  if (id >= BB * DST) return;
  int b = id >> 4, n = id & 15;
  const float* xr = ssm_in + (size_t)b * HIDD;
  const float* br = Bw + (size_t)n * HIDD;
  const float* cr = Cw + (size_t)n * HIDD;
  float ab = 0.f, ac = 0.f;
  #pragma unroll 4
  for (int k = 0; k < HIDD; ++k) { ab += xr[k] * br[k]; ac += xr[k] * cr[k]; }
  Bt[id] = ab; Ct[id] = ac;
}

__global__ void k_state(const float* __restrict__ Delta, const float* __restrict__ ssm_in,
                        const float* __restrict__ A_log, const float* __restrict__ Bt,
                        const float* __restrict__ Ct, const float* __restrict__ Dv,
                        const float* __restrict__ prev, float* __restrict__ state_out,
                        float* __restrict__ belief) {
  int id = blockIdx.x * blockDim.x + threadIdx.x;
  int b = id >> 9, h = id & 511;
  float d = Delta[id], si = ssm_in[id];
  float bel = Dv[h] * si;
  const float* al = A_log + (size_t)h * DST;
  const float* bt = Bt + (size_t)b * DST;
  const float* ct = Ct + (size_t)b * DST;
  const float* sp = prev + (size_t)id * DST;
  float* so = state_out + (size_t)id * DST;
  #pragma unroll
  for (int n = 0; n < DST; ++n) {
    float A = -expf(al[n]);
    float st = expf(d * A) * sp[n] + d * bt[n] * si;
    so[n] = st;
    bel += st * ct[n];
  }
  belief[id] = bel;
}

__global__ void k_prior(const float* __restrict__ belief, const float* __restrict__ w,
                        const float* __restrict__ bias, float* __restrict__ out) {
  int id = blockIdx.x * blockDim.x + threadIdx.x;
  int b = id >> 9, j = id & 511;
  const float* xr = belief + (size_t)b * HIDD;
  const float* wr = w + (size_t)j * HIDD;
  float acc = bias[j];
  #pragma unroll 4
  for (int k = 0; k < HIDD; ++k) acc += xr[k] * wr[k];
  if (j < 256) out[O_MUP + b * 256 + j] = acc;
  else         out[O_LVP + b * 256 + (j - 256)] = acc;
}

// ================= weight prepacks (fragment order) =================
__global__ void k_pack_convw(const float* __restrict__ w, ushort* __restrict__ o,
                             int Cout, int Cin, int n) {
  int id = blockIdx.x * blockDim.x + threadIdx.x;
  if (id >= n) return;
  int NCH = Cin / 2;
  int per = NCH * 512;
  int mt = id / per, r = id % per;
  int kcg = r >> 9, s = r & 511;
  int kg = s >> 7, m = (s >> 3) & 15, k8 = s & 7;
  int co = mt * 16 + m;
  int k = kcg * 32 + kg * 8 + k8;
  int tap = k / Cin, ci = k % Cin;
  o[id] = f2bf(w[(size_t)(co * Cin + ci) * 16 + tap]);
}

__global__ void k_pack_deconvw(const float* __restrict__ w, ushort* __restrict__ o,
                               int Cout, int Cin, int n) {
  int id = blockIdx.x * blockDim.x + threadIdx.x;
  if (id >= n) return;
  int NCH = Cin / 8;
  int perM = NCH * 512;
  int perC = (Cout / 16) * perM;
  int cls = id / perC, r = id % perC;
  int mt = r / perM, r2 = r % perM;
  int kcg = r2 >> 9, s = r2 & 511;
  int kg = s >> 7, m = (s >> 3) & 15, k8 = s & 7;
  int co = mt * 16 + m;
  int k = kcg * 32 + kg * 8 + k8;
  int t = k / Cin, ci = k % Cin;
  int p = (cls >> 1) + 2 * (t >> 1);
  int q = (cls & 1) + 2 * (t & 1);
  o[id] = f2bf(w[(size_t)(ci * Cout + co) * 16 + p * 4 + q]);
}

// ================= img transpose (bf16 out) =================
// img [B,3,256,256] f32 -> timg [3, 65536, B] bf16
__global__ __launch_bounds__(256) void k_timg(const float* __restrict__ img,
                                              ushort* __restrict__ timg) {
  int blk = blockIdx.x;
  int c = blk >> 10, p0 = (blk & 1023) << 6;
  __shared__ float t[64 * 65];
  int tid = threadIdx.x;
  #pragma unroll
  for (int i = 0; i < 16; ++i) {
    int idx = tid + i * 256;
    int b = idx >> 6, pr = idx & 63;
    t[pr * 65 + b] = img[((size_t)b * 3 + c) * 65536 + p0 + pr];
  }
  __syncthreads();
  #pragma unroll
  for (int i = 0; i < 16; ++i) {
    int idx = tid + i * 256;
    int pr = idx >> 6, b = idx & 63;
    timg[((size_t)c * 65536 + p0 + pr) * 64 + b] = f2bf(t[pr * 65 + b]);
  }
}

// ================= conv1: direct (Cin=3), bf16 in, frag-order bf16 out =================
__global__ __launch_bounds__(256) void k_conv1(const ushort* __restrict__ in,
                                               const float* __restrict__ w,
                                               const float* __restrict__ bias,
                                               ushort* __restrict__ out) {
  int wid = __builtin_amdgcn_readfirstlane(blockIdx.x * 4 + (threadIdx.x >> 6));
  int lane = threadIdx.x & 63;
  int x4 = wid & 31; int t = wid >> 5;
  int oy = t & 127; int cg = t >> 7;      // cg 0..3
  int co0 = cg * 8;
  int ox0 = x4 << 2;
  int ixb = ox0 * 2 - 1;
  float acc[8][4];
  #pragma unroll
  for (int u = 0; u < 8; ++u) {
    float bv = bias[co0 + u];
    #pragma unroll
    for (int j = 0; j < 4; ++j) acc[u][j] = bv;
  }
  for (int ci = 0; ci < 3; ++ci) {
    const ushort* ip = in + ((size_t)ci * 65536) * 64 + lane;
    const float* wp = w + (size_t)co0 * 48 + ci * 16;
    #pragma unroll
    for (int ky = 0; ky < 4; ++ky) {
      int iy = oy * 2 - 1 + ky;
      if ((unsigned)iy >= 256u) continue;
      const ushort* rp = ip + (size_t)iy * 256 * 64;
      float x[10];
      #pragma unroll
      for (int j = 0; j < 10; ++j) {
        int ix = ixb + j;
        x[j] = ((unsigned)ix < 256u) ? bf2f(rp[(size_t)ix * 64]) : 0.f;
      }
      #pragma unroll
      for (int u = 0; u < 8; ++u) {
        const float* wq = wp + (size_t)u * 48 + ky * 4;
        float w0 = wq[0], w1 = wq[1], w2 = wq[2], w3 = wq[3];
        acc[u][0] += x[0]*w0 + x[1]*w1 + x[2]*w2 + x[3]*w3;
        acc[u][1] += x[2]*w0 + x[3]*w1 + x[4]*w2 + x[5]*w3;
        acc[u][2] += x[4]*w0 + x[5]*w1 + x[6]*w2 + x[7]*w3;
        acc[u][3] += x[6]*w0 + x[7]*w1 + x[8]*w2 + x[9]*w3;
      }
    }
  }
  #pragma unroll
  for (int j = 0; j < 4; ++j) {
    int px = oy * 128 + ox0 + j;
    size_t off = (size_t)px * 2048 + (size_t)(lane >> 4) * 512 + cg * 128 + (lane & 15) * 8;
    ushort tmp[8];
    #pragma unroll
    for (int u = 0; u < 8; ++u) tmp[u] = f2bf(fmaxf(acc[u][j], 0.f));
    uint4 pk;
    pk.x = tmp[0] | ((unsigned)tmp[1] << 16);
    pk.y = tmp[2] | ((unsigned)tmp[3] << 16);
    pk.z = tmp[4] | ((unsigned)tmp[5] << 16);
    pk.w = tmp[6] | ((unsigned)tmp[7] << 16);
    *(uint4*)(out + off) = pk;
  }
}

// ================= MFMA conv 4x4 s2 p1 + relu (frag-order in/out) =================
template<int CIN, int COUT, int MT>
__global__ __launch_bounds__(256) void mfma_conv(const ushort* __restrict__ in,
                                                 const ushort* __restrict__ wp,
                                                 const float* __restrict__ bias,
                                                 ushort* __restrict__ out,
                                                 int Hin, int Win, int Hout, int Wout) {
  constexpr int NMG = COUT / (16 * MT);
  constexpr int NKC = CIN / 32;
  constexpr int NCH = 16 * NKC;
  int wid = __builtin_amdgcn_readfirstlane(blockIdx.x * 4 + (threadIdx.x >> 6));
  int lane = threadIdx.x & 63;
  int mg = wid % NMG;
  int px = wid / NMG;
  int ox = px % Wout, oy = px / Wout;
  if (oy >= Hout) return;
  int mtile0 = mg * MT;
  f32x4 zero = {0.f, 0.f, 0.f, 0.f};
  f32x4 acc[MT][4];
  #pragma unroll
  for (int mt = 0; mt < MT; ++mt)
    #pragma unroll
    for (int nt = 0; nt < 4; ++nt) acc[mt][nt] = zero;
  const ushort* wbase = wp + (size_t)mtile0 * NCH * 512 + lane * 8;
  const size_t mstride = (size_t)NCH * 512;

  for (int ky = 0; ky < 4; ++ky) {
    int iy = 2 * oy - 1 + ky;
    if ((unsigned)iy >= (unsigned)Hin) continue;
    for (int kx = 0; kx < 4; ++kx) {
      int ix = 2 * ox - 1 + kx;
      if ((unsigned)ix >= (unsigned)Win) continue;
      const ushort* ib = in + (size_t)(iy * Win + ix) * (CIN * 64) + lane * 8;
      int tap = ky * 4 + kx;
      #pragma unroll
      for (int kc = 0; kc < NKC; ++kc) {
        int kcg = tap * NKC + kc;
        bf16x8 a[MT], bb[4];
        #pragma unroll
        for (int mt = 0; mt < MT; ++mt)
          a[mt] = *(const bf16x8*)(wbase + mt * mstride + (size_t)kcg * 512);
        #pragma unroll
        for (int nt = 0; nt < 4; ++nt)
          bb[nt] = *(const bf16x8*)(ib + kc * 2048 + nt * 512);
        #pragma unroll
        for (int mt = 0; mt < MT; ++mt)
          #pragma unroll
          for (int nt = 0; nt < 4; ++nt)
            acc[mt][nt] = __builtin_amdgcn_mfma_f32_16x16x32_bf16(a[mt], bb[nt], acc[mt][nt], 0, 0, 0);
      }
    }
  }
  int ml = lane & 15, rb = (lane >> 4) * 4;
  #pragma unroll
  for (int mt = 0; mt < MT; ++mt) {
    int co = mtile0 * 16 + mt * 16 + rb;
    f32x4 bv = *(const f32x4*)(bias + co);
    #pragma unroll
    for (int nt = 0; nt < 4; ++nt) {
      float v0 = fmaxf(acc[mt][nt][0] + bv[0], 0.f);
      float v1 = fmaxf(acc[mt][nt][1] + bv[1], 0.f);
      float v2 = fmaxf(acc[mt][nt][2] + bv[2], 0.f);
      float v3 = fmaxf(acc[mt][nt][3] + bv[3], 0.f);
      uint2 pk;
      pk.x = (unsigned)f2bf(v0) | ((unsigned)f2bf(v1) << 16);
      pk.y = (unsigned)f2bf(v2) | ((unsigned)f2bf(v3) << 16);
      size_t off = (size_t)px * (COUT * 64) + (size_t)(co >> 5) * 2048 + nt * 512
                 + ((co >> 3) & 3) * 128 + ml * 8 + (co & 7);
      *(uint2*)(out + off) = pk;
    }
  }
}

// ================= MFMA transposed conv 4x4 s2 p1 + relu (frag-order) =================
template<int CIN, int COUT, int MT, bool RELU>
__global__ __launch_bounds__(256) void mfma_deconv(const ushort* __restrict__ in,
                                                   const ushort* __restrict__ wp,
                                                   const float* __restrict__ bias,
                                                   ushort* __restrict__ out,
                                                   int Hin, int Win, int Hout, int Wout) {
  constexpr int NMG = COUT / (16 * MT);
  constexpr int NKC = CIN / 32;
  constexpr int NCH = 4 * NKC;
  constexpr int NTS = (COUT >= 32) ? 512 : (COUT * 16);
  int wid = __builtin_amdgcn_readfirstlane(blockIdx.x * 4 + (threadIdx.x >> 6));
  int lane = threadIdx.x & 63;
  int mg = wid % NMG; int r1 = wid / NMG;
  int wo2 = Wout >> 1;
  int pc = (Hout >> 1) * wo2;
  int pxc = r1 % pc; int cls = r1 / pc;
  if (cls >= 4) return;
  int p0 = cls >> 1, q0 = cls & 1;
  int tx = pxc % wo2, ty = pxc / wo2;
  int oy = 2 * ty + 1 - p0, ox = 2 * tx + 1 - q0;
  int iy0 = (oy + 1 - p0) >> 1, ix0 = (ox + 1 - q0) >> 1;
  int mtile0 = mg * MT;
  f32x4 zero = {0.f, 0.f, 0.f, 0.f};
  f32x4 acc[MT][4];
  #pragma unroll
  for (int mt = 0; mt < MT; ++mt)
    #pragma unroll
    for (int nt = 0; nt < 4; ++nt) acc[mt][nt] = zero;
  const ushort* wbase = wp + ((size_t)cls * (COUT / 16) + mtile0) * NCH * 512 + lane * 8;
  const size_t mstride = (size_t)NCH * 512;

  for (int i = 0; i < 2; ++i) {
    int iy = iy0 - i;
    if ((unsigned)iy >= (unsigned)Hin) continue;
    for (int j = 0; j < 2; ++j) {
      int ix = ix0 - j;
      if ((unsigned)ix >= (unsigned)Win) continue;
      const ushort* ib = in + (size_t)(iy * Win + ix) * (CIN * 64) + lane * 8;
      int tap = i * 2 + j;
      #pragma unroll
      for (int kc = 0; kc < NKC; ++kc) {
        int kcg = tap * NKC + kc;
        bf16x8 a[MT], bb[4];
        #pragma unroll
        for (int mt = 0; mt < MT; ++mt)
          a[mt] = *(const bf16x8*)(wbase + mt * mstride + (size_t)kcg * 512);
        #pragma unroll
        for (int nt = 0; nt < 4; ++nt)
          bb[nt] = *(const bf16x8*)(ib + kc * 2048 + nt * 512);
        #pragma unroll
        for (int mt = 0; mt < MT; ++mt)
          #pragma unroll
          for (int nt = 0; nt < 4; ++nt)
            acc[mt][nt] = __builtin_amdgcn_mfma_f32_16x16x32_bf16(a[mt], bb[nt], acc[mt][nt], 0, 0, 0);
      }
    }
  }
  int ml = lane & 15, rb = (lane >> 4) * 4;
  int px = oy * Wout + ox;
  #pragma unroll
  for (int mt = 0; mt < MT; ++mt) {
    int co = mtile0 * 16 + mt * 16 + rb;
    f32x4 bv = *(const f32x4*)(bias + co);
    #pragma unroll
    for (int nt = 0; nt < 4; ++nt) {
      float v0 = acc[mt][nt][0] + bv[0];
      float v1 = acc[mt][nt][1] + bv[1];
      float v2 = acc[mt][nt][2] + bv[2];
      float v3 = acc[mt][nt][3] + bv[3];
      if (RELU) { v0=fmaxf(v0,0.f); v1=fmaxf(v1,0.f); v2=fmaxf(v2,0.f); v3=fmaxf(v3,0.f); }
      uint2 pk;
      pk.x = (unsigned)f2bf(v0) | ((unsigned)f2bf(v1) << 16);
      pk.y = (unsigned)f2bf(v2) | ((unsigned)f2bf(v3) << 16);
      size_t off = (size_t)px * (COUT * 64) + (size_t)(co >> 5) * 2048 + (size_t)nt * NTS
                 + ((co >> 3) & 3) * 128 + ml * 8 + (co & 7);
      *(uint2*)(out + off) = pk;
    }
  }
}

// ================= enc_fc fused: LDS-transpose staging + MFMA =================
// h4 frag-order [256px][8cc][2048]; wE f32 [512][ci*256+px]
// block = (mg co32, ccf ci32, pxg px16); XCD-swizzled
#define APXS 1032   // A-LDS px stride (u16), 16B-aligned
__global__ __launch_bounds__(256) void k_encfc_fused(const ushort* __restrict__ h4,
                                                     const float* __restrict__ wE,
                                                     float* __restrict__ partial) {
  __shared__ float smem[8320];            // 33,280 B; overlaid ushort A / f32 reduce
  ushort* au = (ushort*)smem;
  int s = blockIdx.x;
  int bid = (s & 7) * 256 + (s >> 3);     // bijective XCD swizzle (2048 % 8 == 0)
  int mg = bid & 15;
  int ccf = (bid >> 4) & 7;
  int pxg = bid >> 7;
  int tid = threadIdx.x;
  int co0 = mg * 32;
  // ---- stage: 32co x 32ci x 16px f32 -> bf16 A-frag order in LDS ----
  #pragma unroll 4
  for (int i = 0; i < 64; ++i) {
    int idx = tid + i * 256;
    int px_l = idx & 15;
    int ci_l = (idx >> 4) & 31;
    int co_l = idx >> 9;
    float v = wE[((size_t)(co0 + co_l) << 16) + (size_t)(ccf * 32 + ci_l) * 256 + pxg * 16 + px_l];
    int mt = co_l >> 4, m = co_l & 15;
    int kg = ci_l >> 3, k8 = ci_l & 7;
    au[px_l * APXS + mt * 512 + kg * 128 + m * 8 + k8] = f2bf(v);
  }
  __syncthreads();
  // ---- MFMA: 4 waves x 4 px each ----
  int lane = tid & 63, wv = tid >> 6;
  int ml = lane & 15, rb = (lane >> 4) * 4;
  f32x4 zero = {0.f, 0.f, 0.f, 0.f};
  f32x4 acc[2][4];
  #pragma unroll
  for (int mt = 0; mt < 2; ++mt)
    #pragma unroll
    for (int nt = 0; nt < 4; ++nt) acc[mt][nt] = zero;
  #pragma unroll
  for (int jj = 0; jj < 4; ++jj) {
    int j = wv * 4 + jj;
    int px = pxg * 16 + j;
    bf16x8 a0 = *(const bf16x8*)(au + j * APXS + lane * 8);
    bf16x8 a1 = *(const bf16x8*)(au + j * APXS + 512 + lane * 8);
    const ushort* hb = h4 + (size_t)px * 16384 + ccf * 2048 + lane * 8;
    bf16x8 bb[4];
    #pragma unroll
    for (int nt = 0; nt < 4; ++nt)
      bb[nt] = *(const bf16x8*)(hb + nt * 512);
    #pragma unroll
    for (int nt = 0; nt < 4; ++nt) {
      acc[0][nt] = __builtin_amdgcn_mfma_f32_16x16x32_bf16(a0, bb[nt], acc[0][nt], 0, 0, 0);
      acc[1][nt] = __builtin_amdgcn_mfma_f32_16x16x32_bf16(a1, bb[nt], acc[1][nt], 0, 0, 0);
    }
  }
  __syncthreads();
  // ---- cross-wave reduce via LDS (f32 view), tile 32co x 64b, row pad 65 ----
  #pragma unroll
  for (int mt = 0; mt < 2; ++mt)
    #pragma unroll
    for (int nt = 0; nt < 4; ++nt)
      #pragma unroll
      for (int r = 0; r < 4; ++r)
        smem[wv * 2080 + (mt * 16 + rb + r) * 65 + nt * 16 + ml] = acc[mt][nt][r];
  __syncthreads();
  int ks = pxg * 8 + ccf;
  #pragma unroll
  for (int i = 0; i < 8; ++i) {
    int e = tid + i * 256;
    int b = e & 63, co_l = e >> 6;
    float sum = smem[co_l * 65 + b] + smem[2080 + co_l * 65 + b]
              + smem[4160 + co_l * 65 + b] + smem[6240 + co_l * 65 + b];
    partial[((size_t)(co0 + co_l) * ENC_KS + ks) * 64 + b] = sum;
  }
}

__global__ void k_encfc_red(const float* __restrict__ partial, const float* __restrict__ bias,
                            float* __restrict__ cnn) {
  int id = blockIdx.x * blockDim.x + threadIdx.x;  // o*64 + b
  int o = id >> 6, b = id & 63;
  float acc = bias[o];
  #pragma unroll 8
  for (int s = 0; s < ENC_KS; ++s) acc += partial[((size_t)o * ENC_KS + s) * 64 + b];
  cnn[(size_t)b * 512 + o] = fmaxf(acc, 0.f);
}

// ================= posterior / reparam =================

__global__ void k_post(const float* __restrict__ cnn, const float* __restrict__ belief,
                       const float* __restrict__ w, const float* __restrict__ bias,
                       float* __restrict__ out) {
  int id = blockIdx.x * blockDim.x + threadIdx.x;
  int b = id >> 9, j = id & 511;
  const float* wr = w + (size_t)j * 1024;
  const float* cr = cnn + (size_t)b * HIDD;
  const float* br = belief + (size_t)b * HIDD;
  float acc = bias[j];
  #pragma unroll 4
  for (int k = 0; k < HIDD; ++k) acc += cr[k] * wr[k];
  #pragma unroll 4
  for (int k = 0; k < HIDD; ++k) acc += br[k] * wr[512 + k];
  if (j < 256) out[O_MUPO + b * 256 + j] = acc;
  else         out[O_LVPO + b * 256 + (j - 256)] = acc;
}

__global__ void k_z(const float* __restrict__ eps, float* __restrict__ out,
                    ushort* __restrict__ zb) {
  int id = blockIdx.x * blockDim.x + threadIdx.x;
  int b = id >> 8, i = id & 255;
  float mu = out[O_MUPO + b * 256 + i];
  float lv = out[O_LVPO + b * 256 + i];
  float z = mu + eps[id] * expf(0.5f * lv);
  out[O_ZT + b * 256 + i] = z;
  if (i < 128) zb[b * 128 + i] = f2bf(z);
}

// ================= dec_fc MFMA: direct f32 weights, frag-order out =================
__global__ __launch_bounds__(256) void k_decfc_mfma(const ushort* __restrict__ zb,
                                                    const float* __restrict__ dfw,
                                                    const float* __restrict__ dfb,
                                                    ushort* __restrict__ dec) {
  int wid = __builtin_amdgcn_readfirstlane(blockIdx.x * 4 + (threadIdx.x >> 6)); // 0..1023
  int lane = threadIdx.x & 63;
  int m0 = wid * 32;
  int ml = lane & 15, kl = (lane >> 4) * 8;
  f32x4 zero = {0.f, 0.f, 0.f, 0.f};
  f32x4 acc[2][4];
  #pragma unroll
  for (int mt = 0; mt < 2; ++mt)
    #pragma unroll
    for (int nt = 0; nt < 4; ++nt) acc[mt][nt] = zero;
  #pragma unroll
  for (int kc = 0; kc < 4; ++kc) {
    bf16x8 a[2], bb[4];
    #pragma unroll
    for (int mt = 0; mt < 2; ++mt) {
      int m_r = m0 + mt * 16 + ml;
      const float* wr = dfw + (size_t)((m_r & 127) * 256 + (m_r >> 7)) * 128 + kc * 32 + kl;
      float4 u0 = *(const float4*)wr;
      float4 u1 = *(const float4*)(wr + 4);
      bf16x8 av;
      av[0] = (short)f2bf(u0.x); av[1] = (short)f2bf(u0.y);
      av[2] = (short)f2bf(u0.z); av[3] = (short)f2bf(u0.w);
      av[4] = (short)f2bf(u1.x); av[5] = (short)f2bf(u1.y);
      av[6] = (short)f2bf(u1.z); av[7] = (short)f2bf(u1.w);
      a[mt] = av;
    }
    #pragma unroll
    for (int nt = 0; nt < 4; ++nt)
      bb[nt] = *(const bf16x8*)(zb + (size_t)(nt * 16 + ml) * 128 + kc * 32 + kl);
    #pragma unroll
    for (int mt = 0; mt < 2; ++mt)
      #pragma unroll
      for (int nt = 0; nt < 4; ++nt)
        acc[mt][nt] = __builtin_amdgcn_mfma_f32_16x16x32_bf16(a[mt], bb[nt], acc[mt][nt], 0, 0, 0);
  }
  int rb = (lane >> 4) * 4;
  #pragma unroll
  for (int mt = 0; mt < 2; ++mt) {
    int m = m0 + mt * 16 + rb;
    int pix = m >> 7, co = m & 127;
    float bv0 = dfb[(size_t)(co + 0) * 256 + pix];
    float bv1 = dfb[(size_t)(co + 1) * 256 + pix];
    float bv2 = dfb[(size_t)(co + 2) * 256 + pix];
    float bv3 = dfb[(size_t)(co + 3) * 256 + pix];
    #pragma unroll
    for (int nt = 0; nt < 4; ++nt) {
      uint2 pk;
      pk.x = (unsigned)f2bf(acc[mt][nt][0] + bv0) | ((unsigned)f2bf(acc[mt][nt][1] + bv1) << 16);
      pk.y = (unsigned)f2bf(acc[mt][nt][2] + bv2) | ((unsigned)f2bf(acc[mt][nt][3] + bv3) << 16);
      size_t off = (size_t)pix * 8192 + (size_t)(co >> 5) * 2048 + nt * 512
                 + ((co >> 3) & 3) * 128 + ml * 8 + (co & 7);
      *(uint2*)(dec + off) = pk;
    }
  }
}

// ================= d4 fused with output transpose =================
__global__ __launch_bounds__(256) void k_d4t(const ushort* __restrict__ in,
                                             const float* __restrict__ w,
                                             const float* __restrict__ bias,
                                             float* __restrict__ out) {
  __shared__ float lds[64][65];
  int blk = blockIdx.x;
  int oy = blk >> 2, ox0 = (blk & 3) << 6;
  int t = threadIdx.x;
  int b = t & 63, sub = t >> 6;
  float bv = bias[0];
  for (int j = 0; j < 16; ++j) {
    int oxl = j * 4 + sub;
    int ox = ox0 + oxl;
    int p0 = (oy + 1) & 1, q0 = (ox + 1) & 1;
    int iy0 = (oy + 1 - p0) >> 1, ix0 = (ox + 1 - q0) >> 1;
    float acc = bv;
    #pragma unroll
    for (int i = 0; i < 2; ++i) {
      int iy = iy0 - i;
      if ((unsigned)iy >= 128u) continue;
      int p = p0 + 2 * i;
      #pragma unroll
      for (int jj = 0; jj < 2; ++jj) {
        int ix = ix0 - jj;
        if ((unsigned)ix >= 128u) continue;
        int q = q0 + 2 * jj;
        const ushort* base = in + (size_t)(iy * 128 + ix) * 1024 + (b >> 4) * 256 + (b & 15) * 8;
        bf16x8 v0 = *(const bf16x8*)(base);
        bf16x8 v1 = *(const bf16x8*)(base + 128);
        const float* wq = w + p * 4 + q;
        #pragma unroll
        for (int ci = 0; ci < 8; ++ci) acc += bf2f((ushort)v0[ci]) * wq[ci * 16];
        #pragma unroll
        for (int ci = 0; ci < 8; ++ci) acc += bf2f((ushort)v1[ci]) * wq[(ci + 8) * 16];
      }
    }
    lds[oxl][b] = acc;
  }
  __syncthreads();
  #pragma unroll
  for (int j = 0; j < 16; ++j) {
    int idx = t + j * 256;
    int b2 = idx >> 6, oxl = idx & 63;
    out[(size_t)b2 * 65536 + oy * 256 + ox0 + oxl] = lds[oxl][b2];
  }
}

// ================= launch =================

extern "C" void kernel_launch(void* const* d_in, const int* in_sizes, int n_in,
                              void* d_out, int out_size, void* d_ws, size_t ws_size,
                              hipStream_t stream) {
  const float* img      = (const float*)d_in[0];
  const float* act      = (const float*)d_in[1];
  const float* z_prev   = (const float*)d_in[2];
  const float* st_prev  = (const float*)d_in[3];
  const float* eps      = (const float*)d_in[4];
  const float* c1w = (const float*)d_in[5];  const float* c1b = (const float*)d_in[6];
  const float* c2w = (const float*)d_in[7];  const float* c2b = (const float*)d_in[8];
  const float* c3w = (const float*)d_in[9];  const float* c3b = (const float*)d_in[10];
  const float* c4w = (const float*)d_in[11]; const float* c4b = (const float*)d_in[12];
  const float* efw = (const float*)d_in[13]; const float* efb = (const float*)d_in[14];
  const float* pow_ = (const float*)d_in[15]; const float* pob = (const float*)d_in[16];
  const float* prw = (const float*)d_in[17]; const float* prb = (const float*)d_in[18];
  const float* siw = (const float*)d_in[19]; const float* sib = (const float*)d_in[20];
  const float* Alog = (const float*)d_in[21];
  const float* Bw = (const float*)d_in[22];  const float* Cw = (const float*)d_in[23];
  const float* Dw = (const float*)d_in[24];  const float* Db = (const float*)d_in[25];
  const float* Dv = (const float*)d_in[26];
  const float* dfw = (const float*)d_in[27]; const float* dfb = (const float*)d_in[28];
  const float* d1w = (const float*)d_in[29]; const float* d1b = (const float*)d_in[30];
  const float* d2w = (const float*)d_in[31]; const float* d2b = (const float*)d_in[32];
  const float* d3w = (const float*)d_in[33]; const float* d3b = (const float*)d_in[34];
  const float* d4w = (const float*)d_in[35]; const float* d4b = (const float*)d_in[36];

  float* ws = (float*)d_ws;
  float* out = (float*)d_out;

  ushort* pc2 = (ushort*)(ws + PW_C2);
  ushort* pc3 = (ushort*)(ws + PW_C3);
  ushort* pc4 = (ushort*)(ws + PW_C4);
  ushort* pd1 = (ushort*)(ws + PW_D1);
  ushort* pd2 = (ushort*)(ws + PW_D2);
  ushort* pd3 = (ushort*)(ws + PW_D3);
  ushort* timgb = (ushort*)(ws + W_TIMG);
  ushort* h1b = (ushort*)(ws + W_H1B);
  ushort* h2b = (ushort*)(ws + W_H2B);
  ushort* h3b = (ushort*)(ws + W_H3B);
  ushort* h4b = (ushort*)(ws + W_H4B);
  ushort* deco = (ushort*)(ws + W_DECO);
  ushort* d1o = (ushort*)(ws + W_D1O);
  ushort* d2o = (ushort*)(ws + W_D2O);
  ushort* d3o = (ushort*)(ws + W_D3O);
  ushort* zb = (ushort*)(ws + W_ZB16);

  // ---- weight prepacks (frag order) ----
  k_pack_convw<<<128, 256, 0, stream>>>(c2w, pc2, 64, 32, 32768);
  k_pack_convw<<<512, 256, 0, stream>>>(c3w, pc3, 128, 64, 131072);
  k_pack_convw<<<2048, 256, 0, stream>>>(c4w, pc4, 256, 128, 524288);
  k_pack_deconvw<<<512, 256, 0, stream>>>(d1w, pd1, 64, 128, 131072);
  k_pack_deconvw<<<128, 256, 0, stream>>>(d2w, pd2, 32, 64, 32768);
  k_pack_deconvw<<<32, 256, 0, stream>>>(d3w, pd3, 16, 32, 8192);

  // ---- SSM chain ----
  k_ssm_in<<<128, 256, 0, stream>>>(z_prev, act, siw, sib, ws + W_SSMIN);
  k_delta<<<128, 256, 0, stream>>>(ws + W_SSMIN, Dw, Db, ws + W_DELTA);
  k_bc<<<4, 256, 0, stream>>>(ws + W_SSMIN, Bw, Cw, ws + W_BT, ws + W_CT);
  k_state<<<128, 256, 0, stream>>>(ws + W_DELTA, ws + W_SSMIN, Alog, ws + W_BT,
                                   ws + W_CT, Dv, st_prev, out + O_STATE, ws + W_BELIEF);
  k_prior<<<128, 256, 0, stream>>>(ws + W_BELIEF, prw, prb, out);

  // ---- encoder ----
  k_timg<<<3072, 256, 0, stream>>>(img, timgb);
  k_conv1<<<4096, 256, 0, stream>>>(timgb, c1w, c1b, h1b);
  mfma_conv<32, 64, 2><<<2048, 256, 0, stream>>>(h1b, pc2, c2b, h2b, 128, 128, 64, 64);
  mfma_conv<64, 128, 2><<<1024, 256, 0, stream>>>(h2b, pc3, c3b, h3b, 64, 64, 32, 32);
  mfma_conv<128, 256, 1><<<1024, 256, 0, stream>>>(h3b, pc4, c4b, h4b, 32, 32, 16, 16);

  // ---- enc_fc (fused transpose+GEMM) ----
  k_encfc_fused<<<2048, 256, 0, stream>>>(h4b, efw, ws + W_ENCP);
  k_encfc_red<<<128, 256, 0, stream>>>(ws + W_ENCP, efb, ws + W_CNN);

  // ---- posterior + reparam ----
  k_post<<<128, 256, 0, stream>>>(ws + W_CNN, ws + W_BELIEF, pow_, pob, out);
  k_z<<<64, 256, 0, stream>>>(eps, out, zb);

  // ---- decoder ----
  k_decfc_mfma<<<256, 256, 0, stream>>>(zb, dfw, dfb, deco);
  mfma_deconv<128, 64, 1, true><<<1024, 256, 0, stream>>>(deco, pd1, d1b, d1o, 16, 16, 32, 32);
  mfma_deconv<64, 32, 1, true><<<2048, 256, 0, stream>>>(d1o, pd2, d2b, d2o, 32, 32, 64, 64);
  mfma_deconv<32, 16, 1, true><<<4096, 256, 0, stream>>>(d2o, pd3, d3b, d3o, 64, 64, 128, 128);
  k_d4t<<<1024, 256, 0, stream>>>(d3o, d4w, d4b, out + O_PRED);
}